// Round 1
// baseline (2328.882 us; speedup 1.0000x reference)
//
#include <hip/hip_runtime.h>
#include <math.h>

#define NS   4
#define NB   256
#define NT   256
#define NH   128
#define NDW  64
#define NFH  48

// ---------------------------------------------------------------------------
// Kernel 1: multi-scale decompose: conv1d(K=5,pad=2) -> BN -> relu, twice.
// One block per scale (4 blocks x 1024 threads). BN stats in f64.
// ---------------------------------------------------------------------------
__global__ __launch_bounds__(1024) void k_decompose(
    const float* __restrict__ x,
    const float* __restrict__ c1w, const float* __restrict__ c1b,
    const float* __restrict__ g1,  const float* __restrict__ b1,
    const float* __restrict__ c2w, const float* __restrict__ c2b,
    const float* __restrict__ g2,  const float* __restrict__ b2,
    float* __restrict__ tmpA, float* __restrict__ tmpB, float* __restrict__ xseq)
{
    const int s   = blockIdx.x;
    const int tid = threadIdx.x;
    const int N   = NB * NT;
    __shared__ double redS[1024];
    __shared__ double redQ[1024];
    __shared__ float  statf[2];

    float w[5];
#pragma unroll
    for (int k = 0; k < 5; ++k) w[k] = c1w[s*5 + k];
    float cb = c1b[s];
    double ls = 0.0, lq = 0.0;
    for (int e = tid; e < N; e += 1024) {
        int bb = e >> 8, t = e & 255;
        const float* xb = x + bb * NT;
        float acc = cb;
#pragma unroll
        for (int k = 0; k < 5; ++k) {
            int tt = t + k - 2;
            if (tt >= 0 && tt < NT) acc += xb[tt] * w[k];
        }
        tmpA[s*N + e] = acc;
        ls += (double)acc; lq += (double)acc * (double)acc;
    }
    redS[tid] = ls; redQ[tid] = lq;
    __syncthreads();
    for (int off = 512; off > 0; off >>= 1) {
        if (tid < off) { redS[tid] += redS[tid+off]; redQ[tid] += redQ[tid+off]; }
        __syncthreads();
    }
    if (tid == 0) {
        double m = redS[0] / N;
        double v = redQ[0] / N - m*m;
        statf[0] = (float)m;
        statf[1] = (float)(1.0 / sqrt(v + 1e-5));
    }
    __syncthreads();
    {
        float m1 = statf[0], is1 = statf[1], gg = g1[s], bo = b1[s];
        for (int e = tid; e < N; e += 1024) {
            float y  = tmpA[s*N + e];
            float hn = gg * (y - m1) * is1 + bo;
            tmpB[s*N + e] = fmaxf(hn, 0.f);
        }
    }
    __syncthreads();
    // stage 2
#pragma unroll
    for (int k = 0; k < 5; ++k) w[k] = c2w[s*5 + k];
    cb = c2b[s];
    ls = 0.0; lq = 0.0;
    for (int e = tid; e < N; e += 1024) {
        int bb = e >> 8, t = e & 255;
        const float* hb = tmpB + s*N + bb*NT;
        float acc = cb;
#pragma unroll
        for (int k = 0; k < 5; ++k) {
            int tt = t + k - 2;
            if (tt >= 0 && tt < NT) acc += hb[tt] * w[k];
        }
        tmpA[s*N + e] = acc;
        ls += (double)acc; lq += (double)acc * (double)acc;
    }
    redS[tid] = ls; redQ[tid] = lq;
    __syncthreads();
    for (int off = 512; off > 0; off >>= 1) {
        if (tid < off) { redS[tid] += redS[tid+off]; redQ[tid] += redQ[tid+off]; }
        __syncthreads();
    }
    if (tid == 0) {
        double m = redS[0] / N;
        double v = redQ[0] / N - m*m;
        statf[0] = (float)m;
        statf[1] = (float)(1.0 / sqrt(v + 1e-5));
    }
    __syncthreads();
    {
        float m2 = statf[0], is2 = statf[1], gg = g2[s], bo = b2[s];
        for (int e = tid; e < N; e += 1024) {
            float y  = tmpA[s*N + e];
            float hn = gg * (y - m2) * is2 + bo;
            xseq[s*N + e] = fmaxf(hn, 0.f);
        }
    }
}

// ---------------------------------------------------------------------------
// Kernel 2: persistent RK4 neural-ODE scan. 256 blocks x 256 threads.
// Block = (scale, 4 batch rows). Weights register-resident per thread:
//   w1 column (tid&63): 130 regs;  w2 column (tid): 64 regs.
// LDS holds only h-in (4x128), u1 (4x64), xseq rows, t_span, mid-indices.
// Thread roles: PhaseA thread=(row=tid>>6, col=tid&63) computes u1[r][c];
//               PhaseB thread=col c (0..255) computes u[0..3][c] and owns
//               the h-state (c<128) or logvar-state (c>=128) for that col.
// ---------------------------------------------------------------------------
__global__ __launch_bounds__(256, 1) void k_ode(
    const float* __restrict__ xseq, const float* __restrict__ tspan,
    const float* __restrict__ dw1, const float* __restrict__ db1,
    const float* __restrict__ dw2, const float* __restrict__ db2,
    float* __restrict__ means, float* __restrict__ logv)
{
    const int s   = blockIdx.x >> 6;
    const int rb  = (blockIdx.x & 63) * 4;
    const int tid = threadIdx.x;
    const int cA  = tid & 63;
    const int rA  = tid >> 6;

    __shared__ __align__(16) float ts[256];
    __shared__ int   imid[255];
    __shared__ __align__(16) float xr[4][256];
    __shared__ __align__(16) float hin[4][128];
    __shared__ __align__(16) float u1[4][64];

    ts[tid] = tspan[tid];
    for (int e = tid; e < 1024; e += 256) {
        int r = e >> 8, t = e & 255;
        xr[r][t] = xseq[(s*NB + rb + r)*NT + t];
    }
    __syncthreads();
    if (tid < 255) {
        // replicate JAX argmin(|t_span - (t0 + dt/2)|) with identical f32 ops
        float t0 = ts[tid], t1 = ts[tid+1];
        float tm = t0 + (t1 - t0) * 0.5f;
        int best = 0; float bd = fabsf(ts[0] - tm);
        for (int j = 1; j < 256; ++j) {
            float d = fabsf(ts[j] - tm);
            if (d < bd) { bd = d; best = j; }
        }
        imid[tid] = best;
    }

    float w1r[130];
#pragma unroll
    for (int k = 0; k < 130; ++k) w1r[k] = dw1[(s*130 + k)*64 + cA];
    float b1r = db1[s*64 + cA];
    float w2r[64];
#pragma unroll
    for (int k = 0; k < 64; ++k) w2r[k] = dw2[(s*64 + k)*256 + tid];
    float b2r = db2[s*256 + tid];

    float st[4]  = {0.f, 0.f, 0.f, 0.f};   // h-state (tid<128) or lv-state
    float acc[4] = {0.f, 0.f, 0.f, 0.f};   // RK4 k-accumulator
    if (tid < 128) {
#pragma unroll
        for (int r = 0; r < 4; ++r) hin[r][tid] = 0.f;
    }
    __syncthreads();

    for (int i = 0; i < 255; ++i) {
        float t0 = ts[i], t1 = ts[i+1];
        float dt = t1 - t0;
        int   im = imid[i];
#pragma unroll
        for (int e = 0; e < 4; ++e) {
            float te; int idx;
            if (e == 0)      { te = t0;                 idx = i;      }
            else if (e == 3) { te = t1;                 idx = i + 1;  }
            else             { te = t0 + dt * 0.5f;     idx = im;     }

            // ---- Phase A: u1[r][c] = relu(z @ w1 + b1), z = [h, x_t, t]
            float xt = xr[rA][idx];
            float a0 = 0.f, a1 = 0.f, a2 = 0.f, a3 = 0.f;
            const float4* h4 = (const float4*)hin[rA];
#pragma unroll
            for (int k4 = 0; k4 < 32; ++k4) {
                float4 hv = h4[k4];
                a0 += hv.x * w1r[4*k4+0];
                a1 += hv.y * w1r[4*k4+1];
                a2 += hv.z * w1r[4*k4+2];
                a3 += hv.w * w1r[4*k4+3];
            }
            float aa = ((a0 + a1) + (a2 + a3)) + b1r + xt * w1r[128] + te * w1r[129];
            u1[rA][cA] = fmaxf(aa, 0.f);
            __syncthreads();

            // ---- Phase B: u[r][c] = u1[r] @ w2 + b2  (c = tid, 4 rows)
            float u[4];
#pragma unroll
            for (int r = 0; r < 4; ++r) u[r] = b2r;
#pragma unroll
            for (int k4 = 0; k4 < 16; ++k4) {
#pragma unroll
                for (int r = 0; r < 4; ++r) {
                    float4 uv = ((const float4*)u1[r])[k4];
                    u[r] += uv.x * w2r[4*k4+0] + uv.y * w2r[4*k4+1]
                          + uv.z * w2r[4*k4+2] + uv.w * w2r[4*k4+3];
                }
            }

            // ---- RK4 state update (cols 0..127 = k_m/h; 128..255 = k_v/lv)
            if (e == 0) {
#pragma unroll
                for (int r = 0; r < 4; ++r) {
                    acc[r] = u[r];
                    if (tid < 128) hin[r][tid] = st[r] + dt * 0.5f * u[r];
                }
            } else if (e == 1) {
#pragma unroll
                for (int r = 0; r < 4; ++r) {
                    acc[r] += 2.f * u[r];
                    if (tid < 128) hin[r][tid] = st[r] + dt * 0.5f * u[r];
                }
            } else if (e == 2) {
#pragma unroll
                for (int r = 0; r < 4; ++r) {
                    acc[r] += 2.f * u[r];
                    if (tid < 128) hin[r][tid] = st[r] + dt * u[r];
                }
            } else {
#pragma unroll
                for (int r = 0; r < 4; ++r) {
                    acc[r] += u[r];
                    st[r]  += (dt / 6.0f) * acc[r];
                    if (tid < 128) hin[r][tid] = st[r];
                }
            }
            __syncthreads();
        }
    }

    if (tid < 128) {
#pragma unroll
        for (int r = 0; r < 4; ++r) means[(s*NB + rb + r)*NH + tid] = st[r];
    } else {
        int c = tid - 128;
#pragma unroll
        for (int r = 0; r < 4; ++r) logv[(s*NB + rb + r)*NH + c] = st[r];
    }
}

// ---------------------------------------------------------------------------
// Kernel 3: fusion (attention over scales) + 48-step GRU decoder.
// One block per batch row (256 blocks x 384 threads). whh row in registers.
// ---------------------------------------------------------------------------
__global__ __launch_bounds__(384, 1) void k_gru(
    const float* __restrict__ means, const float* __restrict__ logvars,
    const float* __restrict__ a1w, const float* __restrict__ a1b,
    const float* __restrict__ a2w, const float* __restrict__ a2b,
    const float* __restrict__ wih, const float* __restrict__ whh,
    const float* __restrict__ bih, const float* __restrict__ bhh,
    const float* __restrict__ fcw, const float* __restrict__ fcb,
    const float* __restrict__ lvw, const float* __restrict__ lvb,
    const float* __restrict__ init_token, float* __restrict__ out)
{
    const int b   = blockIdx.x;
    const int tid = threadIdx.x;

    __shared__ __align__(16) float msh[4][128];
    __shared__ __align__(16) float hl[128];
    __shared__ float ghl[384];
    __shared__ float scoreL[4];
    __shared__ float unc_part[2][4];
    __shared__ float wgt[4];
    __shared__ float redL[2][2];
    __shared__ float tokL;

    for (int e = tid; e < 512; e += 384) {
        int s = e >> 7, i = e & 127;
        msh[s][i] = means[(s*NB + b)*NH + i];
    }
    __syncthreads();

    // uncertainty = mean(exp(logvar)) per scale
    if (tid < 128) {
        int wv = tid >> 6;
#pragma unroll
        for (int s = 0; s < 4; ++s) {
            float v = expf(logvars[(s*NB + b)*NH + tid]);
#pragma unroll
            for (int off = 32; off > 0; off >>= 1) v += __shfl_xor(v, off);
            if ((tid & 63) == 0) unc_part[wv][s] = v;
        }
    }
    // attention scores: relu(means @ a1w + a1b) @ a2w + a2b
    if (tid < 128) {
        int s = tid >> 5, a = tid & 31;
        float hd = a1b[a];
#pragma unroll 4
        for (int i = 0; i < 128; ++i) hd += msh[s][i] * a1w[i*32 + a];
        hd = fmaxf(hd, 0.f);
        float sc = hd * a2w[a];
#pragma unroll
        for (int off = 16; off > 0; off >>= 1) sc += __shfl_xor(sc, off);
        if (a == 0) scoreL[s] = sc + a2b[0];
    }
    __syncthreads();
    if (tid == 0) {
        float sv[4], mx = -1e30f;
#pragma unroll
        for (int s = 0; s < 4; ++s) {
            float u = (unc_part[0][s] + unc_part[1][s]) / 128.f;
            sv[s] = scoreL[s] / (u + 1e-6f);
            mx = fmaxf(mx, sv[s]);
        }
        float se = 0.f, ev[4];
#pragma unroll
        for (int s = 0; s < 4; ++s) { ev[s] = expf(sv[s] - mx); se += ev[s]; }
#pragma unroll
        for (int s = 0; s < 4; ++s) wgt[s] = ev[s] / se;
        tokL = init_token[0];
    }
    __syncthreads();
    if (tid < 128) {
        float f = 0.f;
#pragma unroll
        for (int s = 0; s < 4; ++s) f += wgt[s] * msh[s][tid];
        hl[tid] = f;
    }

    // register-resident GRU weights
    float4 whh4[32];
    const float4* wr = (const float4*)(whh + tid*128);
#pragma unroll
    for (int k = 0; k < 32; ++k) whh4[k] = wr[k];
    float bhhj = bhh[tid];
    float wih_r = 0.f, wih_z = 0.f, wih_n = 0.f;
    float bih_r = 0.f, bih_z = 0.f, bih_n = 0.f;
    float fcwi = 0.f, lvwi = 0.f;
    if (tid < 128) {
        wih_r = wih[tid]; wih_z = wih[128+tid]; wih_n = wih[256+tid];
        bih_r = bih[tid]; bih_z = bih[128+tid]; bih_n = bih[256+tid];
        fcwi  = fcw[tid]; lvwi  = lvw[tid];
    }
    const float fcbv = fcb[0], lvbv = lvb[0];
    __syncthreads();

    for (int t = 0; t < NFH; ++t) {
        float g0 = 0.f, g1 = 0.f, g2 = 0.f, g3 = 0.f;
        const float4* h4 = (const float4*)hl;
#pragma unroll
        for (int k = 0; k < 32; ++k) {
            float4 hv = h4[k];
            float4 wv = whh4[k];
            g0 += hv.x * wv.x; g1 += hv.y * wv.y;
            g2 += hv.z * wv.z; g3 += hv.w * wv.w;
        }
        ghl[tid] = ((g0 + g1) + (g2 + g3)) + bhhj;
        __syncthreads();

        if (tid < 128) {
            float tok = tokL;
            float r  = 1.f / (1.f + expf(-(tok*wih_r + bih_r + ghl[tid])));
            float zz = 1.f / (1.f + expf(-(tok*wih_z + bih_z + ghl[128+tid])));
            float n  = tanhf(tok*wih_n + bih_n + r * ghl[256+tid]);
            float hn = (1.f - zz) * n + zz * hl[tid];
            hl[tid] = hn;
            float pp = hn * fcwi, pl = hn * lvwi;
#pragma unroll
            for (int off = 32; off > 0; off >>= 1) {
                pp += __shfl_xor(pp, off);
                pl += __shfl_xor(pl, off);
            }
            int wv = tid >> 6;
            if ((tid & 63) == 0) { redL[wv][0] = pp; redL[wv][1] = pl; }
        }
        __syncthreads();
        if (tid == 0) {
            float pr = redL[0][0] + redL[1][0] + fcbv;
            float pv = redL[0][1] + redL[1][1] + lvbv;
            out[b*NFH + t] = pr;
            out[NB*NFH + b*NFH + t] = pv;
            tokL = pr;
        }
        __syncthreads();
    }
}

// ---------------------------------------------------------------------------
extern "C" void kernel_launch(void* const* d_in, const int* in_sizes, int n_in,
                              void* d_out, int out_size, void* d_ws, size_t ws_size,
                              hipStream_t stream)
{
    const float* x      = (const float*)d_in[0];
    const float* tspan  = (const float*)d_in[1];
    const float* c1w    = (const float*)d_in[2];
    const float* c1b    = (const float*)d_in[3];
    const float* bn1g   = (const float*)d_in[4];
    const float* bn1b   = (const float*)d_in[5];
    const float* c2w    = (const float*)d_in[6];
    const float* c2b    = (const float*)d_in[7];
    const float* bn2g   = (const float*)d_in[8];
    const float* bn2b   = (const float*)d_in[9];
    const float* dw1    = (const float*)d_in[10];
    const float* db1    = (const float*)d_in[11];
    const float* dw2    = (const float*)d_in[12];
    const float* db2    = (const float*)d_in[13];
    const float* a1w    = (const float*)d_in[14];
    const float* a1b    = (const float*)d_in[15];
    const float* a2w    = (const float*)d_in[16];
    const float* a2b    = (const float*)d_in[17];
    const float* wih    = (const float*)d_in[18];
    const float* whh    = (const float*)d_in[19];
    const float* bih    = (const float*)d_in[20];
    const float* bhh    = (const float*)d_in[21];
    const float* fcw    = (const float*)d_in[22];
    const float* fcb    = (const float*)d_in[23];
    const float* lvw    = (const float*)d_in[24];
    const float* lvb    = (const float*)d_in[25];
    const float* itok   = (const float*)d_in[26];

    float* ws    = (float*)d_ws;
    float* xseq  = ws;                 // 4*256*256      = 262144
    float* tmpA  = ws + 262144;        // 262144
    float* tmpB  = ws + 524288;        // 262144
    float* means = ws + 786432;        // 4*256*128      = 131072
    float* logv  = ws + 917504;        // 131072

    k_decompose<<<4, 1024, 0, stream>>>(x, c1w, c1b, bn1g, bn1b,
                                        c2w, c2b, bn2g, bn2b,
                                        tmpA, tmpB, xseq);
    k_ode<<<256, 256, 0, stream>>>(xseq, tspan, dw1, db1, dw2, db2, means, logv);
    k_gru<<<256, 384, 0, stream>>>(means, logv, a1w, a1b, a2w, a2b,
                                   wih, whh, bih, bhh, fcw, fcb, lvw, lvb,
                                   itok, (float*)d_out);
}

// Round 2
// 1252.043 us; speedup vs baseline: 1.8601x; 1.8601x over previous
//
#include <hip/hip_runtime.h>
#include <math.h>

#define NS   4
#define NB   256
#define NT   256
#define NH   128
#define NDW  64
#define NFH  48

// ---------------------------------------------------------------------------
// Kernel 1: multi-scale decompose: conv1d(K=5,pad=2) -> BN -> relu, twice.
// One block per scale (4 blocks x 1024 threads). BN stats in f64.
// ---------------------------------------------------------------------------
__global__ __launch_bounds__(1024) void k_decompose(
    const float* __restrict__ x,
    const float* __restrict__ c1w, const float* __restrict__ c1b,
    const float* __restrict__ g1,  const float* __restrict__ b1,
    const float* __restrict__ c2w, const float* __restrict__ c2b,
    const float* __restrict__ g2,  const float* __restrict__ b2,
    float* __restrict__ tmpA, float* __restrict__ tmpB, float* __restrict__ xseq)
{
    const int s   = blockIdx.x;
    const int tid = threadIdx.x;
    const int N   = NB * NT;
    __shared__ double redS[1024];
    __shared__ double redQ[1024];
    __shared__ float  statf[2];

    float w[5];
#pragma unroll
    for (int k = 0; k < 5; ++k) w[k] = c1w[s*5 + k];
    float cb = c1b[s];
    double ls = 0.0, lq = 0.0;
    for (int e = tid; e < N; e += 1024) {
        int bb = e >> 8, t = e & 255;
        const float* xb = x + bb * NT;
        float acc = cb;
#pragma unroll
        for (int k = 0; k < 5; ++k) {
            int tt = t + k - 2;
            if (tt >= 0 && tt < NT) acc += xb[tt] * w[k];
        }
        tmpA[s*N + e] = acc;
        ls += (double)acc; lq += (double)acc * (double)acc;
    }
    redS[tid] = ls; redQ[tid] = lq;
    __syncthreads();
    for (int off = 512; off > 0; off >>= 1) {
        if (tid < off) { redS[tid] += redS[tid+off]; redQ[tid] += redQ[tid+off]; }
        __syncthreads();
    }
    if (tid == 0) {
        double m = redS[0] / N;
        double v = redQ[0] / N - m*m;
        statf[0] = (float)m;
        statf[1] = (float)(1.0 / sqrt(v + 1e-5));
    }
    __syncthreads();
    {
        float m1 = statf[0], is1 = statf[1], gg = g1[s], bo = b1[s];
        for (int e = tid; e < N; e += 1024) {
            float y  = tmpA[s*N + e];
            float hn = gg * (y - m1) * is1 + bo;
            tmpB[s*N + e] = fmaxf(hn, 0.f);
        }
    }
    __syncthreads();
    // stage 2
#pragma unroll
    for (int k = 0; k < 5; ++k) w[k] = c2w[s*5 + k];
    cb = c2b[s];
    ls = 0.0; lq = 0.0;
    for (int e = tid; e < N; e += 1024) {
        int bb = e >> 8, t = e & 255;
        const float* hb = tmpB + s*N + bb*NT;
        float acc = cb;
#pragma unroll
        for (int k = 0; k < 5; ++k) {
            int tt = t + k - 2;
            if (tt >= 0 && tt < NT) acc += hb[tt] * w[k];
        }
        tmpA[s*N + e] = acc;
        ls += (double)acc; lq += (double)acc * (double)acc;
    }
    redS[tid] = ls; redQ[tid] = lq;
    __syncthreads();
    for (int off = 512; off > 0; off >>= 1) {
        if (tid < off) { redS[tid] += redS[tid+off]; redQ[tid] += redQ[tid+off]; }
        __syncthreads();
    }
    if (tid == 0) {
        double m = redS[0] / N;
        double v = redQ[0] / N - m*m;
        statf[0] = (float)m;
        statf[1] = (float)(1.0 / sqrt(v + 1e-5));
    }
    __syncthreads();
    {
        float m2 = statf[0], is2 = statf[1], gg = g2[s], bo = b2[s];
        for (int e = tid; e < N; e += 1024) {
            float y  = tmpA[s*N + e];
            float hn = gg * (y - m2) * is2 + bo;
            xseq[s*N + e] = fmaxf(hn, 0.f);
        }
    }
}

// ---------------------------------------------------------------------------
// Kernel 2: persistent RK4 neural-ODE scan, v2.
// 1024 blocks x 256 threads: block = one (scale, batch-row). 4 blocks/CU ->
// 4 waves/SIMD so barrier/LDS stalls of one block hide under the others.
// Per eval, 3 phases:
//   P1: wave q computes k-chunk partial of u1[c]=z@w1 (32 regs w1 chunk/thread)
//   P2: wave 0 reduces 4 partials, relu -> u1[64] in LDS
//   P3: thread tid computes u[tid] = u1 @ w2 col tid (64 regs w2/thread);
//       thread tid owns RK4 state col tid (h for tid<128, logvar for >=128).
// All LDS reads are wave-uniform broadcasts or stride-1 (conflict-free).
// ---------------------------------------------------------------------------
__global__ __launch_bounds__(256, 4) void k_ode(
    const float* __restrict__ xseq, const float* __restrict__ tspan,
    const float* __restrict__ dw1, const float* __restrict__ db1,
    const float* __restrict__ dw2, const float* __restrict__ db2,
    float* __restrict__ means, float* __restrict__ logv)
{
    const int b   = blockIdx.x;
    const int s   = b >> 8;
    const int row = b & 255;
    const int tid = threadIdx.x;
    const int q   = tid >> 6;      // wave index = k-chunk for P1
    const int c   = tid & 63;      // column within u1 for P1

    __shared__ __align__(16) float ts[256];
    __shared__ int   imid[255];
    __shared__ __align__(16) float xr[256];
    __shared__ __align__(16) float hin[128];
    __shared__ __align__(16) float u1[64];
    __shared__ float pA[4][64];

    ts[tid] = tspan[tid];
    xr[tid] = xseq[(s*NB + row)*NT + tid];
    if (tid < 128) hin[tid] = 0.f;
    __syncthreads();
    if (tid < 255) {
        // replicate JAX argmin(|t_span - (t0 + dt/2)|), first-min-wins
        float t0 = ts[tid], t1 = ts[tid+1];
        float tm = t0 + (t1 - t0) * 0.5f;
        int best = 0; float bd = fabsf(ts[0] - tm);
        for (int j = 1; j < 256; ++j) {
            float d = fabsf(ts[j] - tm);
            if (d < bd) { bd = d; best = j; }
        }
        imid[tid] = best;
    }

    // register-resident weights
    float w1c[32];
#pragma unroll
    for (int j = 0; j < 32; ++j) w1c[j] = dw1[(s*130 + 32*q + j)*64 + c];
    float w1x = 0.f, w1t = 0.f, b1c = 0.f;
    if (q == 0) {
        w1x = dw1[(s*130 + 128)*64 + c];
        w1t = dw1[(s*130 + 129)*64 + c];
        b1c = db1[s*64 + c];
    }
    float w2r[64];
#pragma unroll
    for (int k = 0; k < 64; ++k) w2r[k] = dw2[(s*64 + k)*256 + tid];
    const float b2r = db2[s*256 + tid];

    float st = 0.f, acc = 0.f;    // this thread's state col + RK4 accumulator
    __syncthreads();              // imid + hin visible

    for (int i = 0; i < 255; ++i) {
        float t0 = ts[i], t1 = ts[i+1];
        float dt = t1 - t0;
        int   im = imid[i];
#pragma unroll
        for (int e = 0; e < 4; ++e) {
            float te; int idx;
            if (e == 0)      { te = t0;             idx = i;     }
            else if (e == 3) { te = t1;             idx = i + 1; }
            else             { te = t0 + dt * 0.5f; idx = im;    }

            // ---- P1: partial dot over this wave's 32-dim h chunk (broadcast)
            float a0 = 0.f, a1 = 0.f, a2 = 0.f, a3 = 0.f;
            const float4* h4 = (const float4*)(hin + 32*q);
#pragma unroll
            for (int k4 = 0; k4 < 8; ++k4) {
                float4 hv = h4[k4];
                a0 += hv.x * w1c[4*k4+0];
                a1 += hv.y * w1c[4*k4+1];
                a2 += hv.z * w1c[4*k4+2];
                a3 += hv.w * w1c[4*k4+3];
            }
            float aa = (a0 + a1) + (a2 + a3);
            if (q == 0) {
                float xt = xr[idx];
                aa += b1c + xt * w1x + te * w1t;
            }
            pA[q][c] = aa;
            __syncthreads();

            // ---- P2: reduce partials + relu -> u1 (wave 0 only)
            if (tid < 64) {
                float v = pA[0][tid] + pA[1][tid] + pA[2][tid] + pA[3][tid];
                u1[tid] = fmaxf(v, 0.f);
            }
            __syncthreads();

            // ---- P3: u[tid] = u1 @ w2 col tid (uniform broadcast reads)
            float u = b2r;
            const float4* u4 = (const float4*)u1;
#pragma unroll
            for (int k4 = 0; k4 < 16; ++k4) {
                float4 uv = u4[k4];
                u += uv.x * w2r[4*k4+0] + uv.y * w2r[4*k4+1]
                   + uv.z * w2r[4*k4+2] + uv.w * w2r[4*k4+3];
            }

            // ---- RK4 update: thread owns its state column
            float hnext;
            if (e == 0)      { acc  = u;           hnext = st + dt * 0.5f * u; }
            else if (e == 1) { acc += 2.f * u;     hnext = st + dt * 0.5f * u; }
            else if (e == 2) { acc += 2.f * u;     hnext = st + dt * u;        }
            else             { acc += u; st += (dt / 6.0f) * acc; hnext = st;  }
            if (tid < 128) hin[tid] = hnext;
            __syncthreads();
        }
    }

    if (tid < 128) means[(s*NB + row)*NH + tid]         = st;
    else           logv[(s*NB + row)*NH + (tid - 128)]  = st;
}

// ---------------------------------------------------------------------------
// Kernel 3: fusion (attention over scales) + 48-step GRU decoder.
// One block per batch row (256 blocks x 384 threads). whh row in registers.
// ---------------------------------------------------------------------------
__global__ __launch_bounds__(384, 1) void k_gru(
    const float* __restrict__ means, const float* __restrict__ logvars,
    const float* __restrict__ a1w, const float* __restrict__ a1b,
    const float* __restrict__ a2w, const float* __restrict__ a2b,
    const float* __restrict__ wih, const float* __restrict__ whh,
    const float* __restrict__ bih, const float* __restrict__ bhh,
    const float* __restrict__ fcw, const float* __restrict__ fcb,
    const float* __restrict__ lvw, const float* __restrict__ lvb,
    const float* __restrict__ init_token, float* __restrict__ out)
{
    const int b   = blockIdx.x;
    const int tid = threadIdx.x;

    __shared__ __align__(16) float msh[4][128];
    __shared__ __align__(16) float hl[128];
    __shared__ float ghl[384];
    __shared__ float scoreL[4];
    __shared__ float unc_part[2][4];
    __shared__ float wgt[4];
    __shared__ float redL[2][2];
    __shared__ float tokL;

    for (int e = tid; e < 512; e += 384) {
        int s = e >> 7, i = e & 127;
        msh[s][i] = means[(s*NB + b)*NH + i];
    }
    __syncthreads();

    // uncertainty = mean(exp(logvar)) per scale
    if (tid < 128) {
        int wv = tid >> 6;
#pragma unroll
        for (int s = 0; s < 4; ++s) {
            float v = expf(logvars[(s*NB + b)*NH + tid]);
#pragma unroll
            for (int off = 32; off > 0; off >>= 1) v += __shfl_xor(v, off);
            if ((tid & 63) == 0) unc_part[wv][s] = v;
        }
    }
    // attention scores: relu(means @ a1w + a1b) @ a2w + a2b
    if (tid < 128) {
        int s = tid >> 5, a = tid & 31;
        float hd = a1b[a];
#pragma unroll 4
        for (int i = 0; i < 128; ++i) hd += msh[s][i] * a1w[i*32 + a];
        hd = fmaxf(hd, 0.f);
        float sc = hd * a2w[a];
#pragma unroll
        for (int off = 16; off > 0; off >>= 1) sc += __shfl_xor(sc, off);
        if (a == 0) scoreL[s] = sc + a2b[0];
    }
    __syncthreads();
    if (tid == 0) {
        float sv[4], mx = -1e30f;
#pragma unroll
        for (int s = 0; s < 4; ++s) {
            float u = (unc_part[0][s] + unc_part[1][s]) / 128.f;
            sv[s] = scoreL[s] / (u + 1e-6f);
            mx = fmaxf(mx, sv[s]);
        }
        float se = 0.f, ev[4];
#pragma unroll
        for (int s = 0; s < 4; ++s) { ev[s] = expf(sv[s] - mx); se += ev[s]; }
#pragma unroll
        for (int s = 0; s < 4; ++s) wgt[s] = ev[s] / se;
        tokL = init_token[0];
    }
    __syncthreads();
    if (tid < 128) {
        float f = 0.f;
#pragma unroll
        for (int s = 0; s < 4; ++s) f += wgt[s] * msh[s][tid];
        hl[tid] = f;
    }

    // register-resident GRU weights
    float4 whh4[32];
    const float4* wr = (const float4*)(whh + tid*128);
#pragma unroll
    for (int k = 0; k < 32; ++k) whh4[k] = wr[k];
    float bhhj = bhh[tid];
    float wih_r = 0.f, wih_z = 0.f, wih_n = 0.f;
    float bih_r = 0.f, bih_z = 0.f, bih_n = 0.f;
    float fcwi = 0.f, lvwi = 0.f;
    if (tid < 128) {
        wih_r = wih[tid]; wih_z = wih[128+tid]; wih_n = wih[256+tid];
        bih_r = bih[tid]; bih_z = bih[128+tid]; bih_n = bih[256+tid];
        fcwi  = fcw[tid]; lvwi  = lvw[tid];
    }
    const float fcbv = fcb[0], lvbv = lvb[0];
    __syncthreads();

    for (int t = 0; t < NFH; ++t) {
        float g0 = 0.f, g1 = 0.f, g2 = 0.f, g3 = 0.f;
        const float4* h4 = (const float4*)hl;
#pragma unroll
        for (int k = 0; k < 32; ++k) {
            float4 hv = h4[k];
            float4 wv = whh4[k];
            g0 += hv.x * wv.x; g1 += hv.y * wv.y;
            g2 += hv.z * wv.z; g3 += hv.w * wv.w;
        }
        ghl[tid] = ((g0 + g1) + (g2 + g3)) + bhhj;
        __syncthreads();

        if (tid < 128) {
            float tok = tokL;
            float r  = 1.f / (1.f + expf(-(tok*wih_r + bih_r + ghl[tid])));
            float zz = 1.f / (1.f + expf(-(tok*wih_z + bih_z + ghl[128+tid])));
            float n  = tanhf(tok*wih_n + bih_n + r * ghl[256+tid]);
            float hn = (1.f - zz) * n + zz * hl[tid];
            hl[tid] = hn;
            float pp = hn * fcwi, pl = hn * lvwi;
#pragma unroll
            for (int off = 32; off > 0; off >>= 1) {
                pp += __shfl_xor(pp, off);
                pl += __shfl_xor(pl, off);
            }
            int wv = tid >> 6;
            if ((tid & 63) == 0) { redL[wv][0] = pp; redL[wv][1] = pl; }
        }
        __syncthreads();
        if (tid == 0) {
            float pr = redL[0][0] + redL[1][0] + fcbv;
            float pv = redL[0][1] + redL[1][1] + lvbv;
            out[b*NFH + t] = pr;
            out[NB*NFH + b*NFH + t] = pv;
            tokL = pr;
        }
        __syncthreads();
    }
}

// ---------------------------------------------------------------------------
extern "C" void kernel_launch(void* const* d_in, const int* in_sizes, int n_in,
                              void* d_out, int out_size, void* d_ws, size_t ws_size,
                              hipStream_t stream)
{
    const float* x      = (const float*)d_in[0];
    const float* tspan  = (const float*)d_in[1];
    const float* c1w    = (const float*)d_in[2];
    const float* c1b    = (const float*)d_in[3];
    const float* bn1g   = (const float*)d_in[4];
    const float* bn1b   = (const float*)d_in[5];
    const float* c2w    = (const float*)d_in[6];
    const float* c2b    = (const float*)d_in[7];
    const float* bn2g   = (const float*)d_in[8];
    const float* bn2b   = (const float*)d_in[9];
    const float* dw1    = (const float*)d_in[10];
    const float* db1    = (const float*)d_in[11];
    const float* dw2    = (const float*)d_in[12];
    const float* db2    = (const float*)d_in[13];
    const float* a1w    = (const float*)d_in[14];
    const float* a1b    = (const float*)d_in[15];
    const float* a2w    = (const float*)d_in[16];
    const float* a2b    = (const float*)d_in[17];
    const float* wih    = (const float*)d_in[18];
    const float* whh    = (const float*)d_in[19];
    const float* bih    = (const float*)d_in[20];
    const float* bhh    = (const float*)d_in[21];
    const float* fcw    = (const float*)d_in[22];
    const float* fcb    = (const float*)d_in[23];
    const float* lvw    = (const float*)d_in[24];
    const float* lvb    = (const float*)d_in[25];
    const float* itok   = (const float*)d_in[26];

    float* ws    = (float*)d_ws;
    float* xseq  = ws;                 // 4*256*256      = 262144
    float* tmpA  = ws + 262144;        // 262144
    float* tmpB  = ws + 524288;        // 262144
    float* means = ws + 786432;        // 4*256*128      = 131072
    float* logv  = ws + 917504;        // 131072

    k_decompose<<<4, 1024, 0, stream>>>(x, c1w, c1b, bn1g, bn1b,
                                        c2w, c2b, bn2g, bn2b,
                                        tmpA, tmpB, xseq);
    k_ode<<<1024, 256, 0, stream>>>(xseq, tspan, dw1, db1, dw2, db2, means, logv);
    k_gru<<<256, 384, 0, stream>>>(means, logv, a1w, a1b, a2w, a2b,
                                   wih, whh, bih, bhh, fcw, fcb, lvw, lvb,
                                   itok, (float*)d_out);
}

// Round 3
// 1129.501 us; speedup vs baseline: 2.0619x; 1.1085x over previous
//
#include <hip/hip_runtime.h>
#include <math.h>

#define NS   4
#define NB   256
#define NT   256
#define NH   128
#define NDW  64
#define NFH  48

// ---------------------------------------------------------------------------
// Kernel 1: multi-scale decompose: conv1d(K=5,pad=2) -> BN -> relu, twice.
// One block per scale (4 blocks x 1024 threads). BN stats in f64.
// ---------------------------------------------------------------------------
__global__ __launch_bounds__(1024) void k_decompose(
    const float* __restrict__ x,
    const float* __restrict__ c1w, const float* __restrict__ c1b,
    const float* __restrict__ g1,  const float* __restrict__ b1,
    const float* __restrict__ c2w, const float* __restrict__ c2b,
    const float* __restrict__ g2,  const float* __restrict__ b2,
    float* __restrict__ tmpA, float* __restrict__ tmpB, float* __restrict__ xseq)
{
    const int s   = blockIdx.x;
    const int tid = threadIdx.x;
    const int N   = NB * NT;
    __shared__ double redS[1024];
    __shared__ double redQ[1024];
    __shared__ float  statf[2];

    float w[5];
#pragma unroll
    for (int k = 0; k < 5; ++k) w[k] = c1w[s*5 + k];
    float cb = c1b[s];
    double ls = 0.0, lq = 0.0;
    for (int e = tid; e < N; e += 1024) {
        int bb = e >> 8, t = e & 255;
        const float* xb = x + bb * NT;
        float acc = cb;
#pragma unroll
        for (int k = 0; k < 5; ++k) {
            int tt = t + k - 2;
            if (tt >= 0 && tt < NT) acc += xb[tt] * w[k];
        }
        tmpA[s*N + e] = acc;
        ls += (double)acc; lq += (double)acc * (double)acc;
    }
    redS[tid] = ls; redQ[tid] = lq;
    __syncthreads();
    for (int off = 512; off > 0; off >>= 1) {
        if (tid < off) { redS[tid] += redS[tid+off]; redQ[tid] += redQ[tid+off]; }
        __syncthreads();
    }
    if (tid == 0) {
        double m = redS[0] / N;
        double v = redQ[0] / N - m*m;
        statf[0] = (float)m;
        statf[1] = (float)(1.0 / sqrt(v + 1e-5));
    }
    __syncthreads();
    {
        float m1 = statf[0], is1 = statf[1], gg = g1[s], bo = b1[s];
        for (int e = tid; e < N; e += 1024) {
            float y  = tmpA[s*N + e];
            float hn = gg * (y - m1) * is1 + bo;
            tmpB[s*N + e] = fmaxf(hn, 0.f);
        }
    }
    __syncthreads();
    // stage 2
#pragma unroll
    for (int k = 0; k < 5; ++k) w[k] = c2w[s*5 + k];
    cb = c2b[s];
    ls = 0.0; lq = 0.0;
    for (int e = tid; e < N; e += 1024) {
        int bb = e >> 8, t = e & 255;
        const float* hb = tmpB + s*N + bb*NT;
        float acc = cb;
#pragma unroll
        for (int k = 0; k < 5; ++k) {
            int tt = t + k - 2;
            if (tt >= 0 && tt < NT) acc += hb[tt] * w[k];
        }
        tmpA[s*N + e] = acc;
        ls += (double)acc; lq += (double)acc * (double)acc;
    }
    redS[tid] = ls; redQ[tid] = lq;
    __syncthreads();
    for (int off = 512; off > 0; off >>= 1) {
        if (tid < off) { redS[tid] += redS[tid+off]; redQ[tid] += redQ[tid+off]; }
        __syncthreads();
    }
    if (tid == 0) {
        double m = redS[0] / N;
        double v = redQ[0] / N - m*m;
        statf[0] = (float)m;
        statf[1] = (float)(1.0 / sqrt(v + 1e-5));
    }
    __syncthreads();
    {
        float m2 = statf[0], is2 = statf[1], gg = g2[s], bo = b2[s];
        for (int e = tid; e < N; e += 1024) {
            float y  = tmpA[s*N + e];
            float hn = gg * (y - m2) * is2 + bo;
            xseq[s*N + e] = fmaxf(hn, 0.f);
        }
    }
}

// ---------------------------------------------------------------------------
// Kernel 1b: precompute the JAX argmin(|t_span - tm|) midpoint index table
// (identical f32 ops, first-min-wins). All ODE blocks used to compute this
// redundantly; now it's done once and k_ode s_loads it.
// ---------------------------------------------------------------------------
__global__ void k_prep(const float* __restrict__ tspan, int* __restrict__ imid_g)
{
    __shared__ float ts[256];
    const int tid = threadIdx.x;
    ts[tid] = tspan[tid];
    __syncthreads();
    if (tid < 255) {
        float t0 = ts[tid], t1 = ts[tid+1];
        float tm = t0 + (t1 - t0) * 0.5f;
        int best = 0; float bd = fabsf(ts[0] - tm);
        for (int j = 1; j < 256; ++j) {
            float d = fabsf(ts[j] - tm);
            if (d < bd) { bd = d; best = j; }
        }
        imid_g[tid] = best;
    }
}

// ---------------------------------------------------------------------------
// Kernel 2: persistent RK4 neural-ODE scan, v3.
// 1024 blocks x 256 threads, block = one (scale,row), 4 blocks/CU.
// Weights REGISTER-RESIDENT and pinned via asm laundering (~106 regs):
//   P1 role: lane -> (chunk q = lane>>4, col cc = wave*16 + lane&15);
//            w1 chunk = 8 float4 (32 regs) + 3 tail regs.
//   P3 role: thread tid owns output column tid; w2 column = 16 float4.
// Per eval: P1 dot (LDS hin, conflict-free transposed layout) -> 2x shfl_xor
// cross-chunk reduce -> u1 write -> bar -> P3 dot (broadcast u1 reads) ->
// RK4 state update -> bar.  2 barriers/eval.
// Wave-uniform values (t0,t1,imid,x_t) come from uniform global loads
// (scalar pipe) instead of LDS.
// ---------------------------------------------------------------------------
__global__ __launch_bounds__(256, 4) void k_ode(
    const float* __restrict__ xseq, const float* __restrict__ tspan,
    const int*   __restrict__ imid_g,
    const float* __restrict__ dw1, const float* __restrict__ db1,
    const float* __restrict__ dw2, const float* __restrict__ db2,
    float* __restrict__ means, float* __restrict__ logv)
{
    const int b    = blockIdx.x;
    const int s    = b >> 8;
    const int row  = b & 255;
    const int tid  = threadIdx.x;
    const int wv   = tid >> 6;
    const int lane = tid & 63;
    const int q    = lane >> 4;              // k-chunk for P1
    const int cc   = (wv << 4) | (lane & 15); // u1 column for P1

    // hin physical layout: logical k -> chunk q=k>>5, f4 j=(k>>2)&7, m=k&3
    // physical float4 slot = j*4 + q  => P1 read addr = base + q*16 + j*64
    // (per b128 read the 4 q-groups hit 16 consecutive banks: conflict-free)
    __shared__ __align__(16) float hin[128];
    __shared__ __align__(16) float u1[64];

    const float* __restrict__ xrow = xseq + (s*NB + row)*NT;

    // ---- register-resident weights
    float4 w1c4[8];
#pragma unroll
    for (int j = 0; j < 8; ++j) {
        w1c4[j].x = dw1[(s*130 + 32*q + 4*j + 0)*64 + cc];
        w1c4[j].y = dw1[(s*130 + 32*q + 4*j + 1)*64 + cc];
        w1c4[j].z = dw1[(s*130 + 32*q + 4*j + 2)*64 + cc];
        w1c4[j].w = dw1[(s*130 + 32*q + 4*j + 3)*64 + cc];
    }
    float w1x = 0.f, w1t = 0.f, b1c = 0.f;
    if (q == 0) {
        w1x = dw1[(s*130 + 128)*64 + cc];
        w1t = dw1[(s*130 + 129)*64 + cc];
        b1c = db1[s*64 + cc];
    }
    float4 w2r4[16];
#pragma unroll
    for (int k4 = 0; k4 < 16; ++k4) {
        w2r4[k4].x = dw2[(s*64 + 4*k4 + 0)*256 + tid];
        w2r4[k4].y = dw2[(s*64 + 4*k4 + 1)*256 + tid];
        w2r4[k4].z = dw2[(s*64 + 4*k4 + 2)*256 + tid];
        w2r4[k4].w = dw2[(s*64 + 4*k4 + 3)*256 + tid];
    }
    const float b2r = db2[s*256 + tid];

    // launder: make weight values opaque so the compiler cannot re-load them
    // from global inside the loop (R1 failure mode: remat -> 3.6GB fetch)
#pragma unroll
    for (int j = 0; j < 8; ++j)
        asm volatile("" : "+v"(w1c4[j].x), "+v"(w1c4[j].y),
                          "+v"(w1c4[j].z), "+v"(w1c4[j].w));
    asm volatile("" : "+v"(w1x), "+v"(w1t), "+v"(b1c));
#pragma unroll
    for (int k4 = 0; k4 < 16; ++k4)
        asm volatile("" : "+v"(w2r4[k4].x), "+v"(w2r4[k4].y),
                          "+v"(w2r4[k4].z), "+v"(w2r4[k4].w));

    // physical word index of this thread's h column (bijective over [0,128))
    const int hw = ((tid >> 2) & 7)*16 + (tid >> 5)*4 + (tid & 3);
    if (tid < 128) hin[hw] = 0.f;
    __syncthreads();

    float st = 0.f, acc = 0.f;

    for (int i = 0; i < 255; ++i) {
        const float t0 = tspan[i];
        const float t1 = tspan[i+1];
        const float dt = t1 - t0;
        const int   im = imid_g[i];
#pragma unroll
        for (int e = 0; e < 4; ++e) {
            float te; int idx;
            if (e == 0)      { te = t0;             idx = i;     }
            else if (e == 3) { te = t1;             idx = i + 1; }
            else             { te = t0 + dt * 0.5f; idx = im;    }
            const float xt = xrow[idx];    // uniform -> scalar load

            // ---- P1: chunk-partial dot (conflict-free b128 LDS reads)
            float a0 = 0.f, a1 = 0.f, a2 = 0.f, a3 = 0.f;
            const float4* hp = ((const float4*)hin) + q;
#pragma unroll
            for (int j = 0; j < 8; ++j) {
                float4 hv = hp[4*j];
                a0 += hv.x * w1c4[j].x;
                a1 += hv.y * w1c4[j].y;
                a2 += hv.z * w1c4[j].z;
                a3 += hv.w * w1c4[j].w;
            }
            float aa = (a0 + a1) + (a2 + a3);
            aa += __shfl_xor(aa, 16);
            aa += __shfl_xor(aa, 32);
            if (q == 0) {
                aa += b1c + xt * w1x + te * w1t;
                u1[cc] = fmaxf(aa, 0.f);
            }
            __syncthreads();

            // ---- P3: u[tid] = u1 @ w2col(tid)  (broadcast u1 reads)
            float u = b2r;
            const float4* u4 = (const float4*)u1;
#pragma unroll
            for (int k4 = 0; k4 < 16; ++k4) {
                float4 uv = u4[k4];
                u += uv.x * w2r4[k4].x + uv.y * w2r4[k4].y
                   + uv.z * w2r4[k4].z + uv.w * w2r4[k4].w;
            }

            // ---- RK4 update: thread owns its state column
            float hnext;
            if (e == 0)      { acc  = u;           hnext = st + dt * 0.5f * u; }
            else if (e == 1) { acc += 2.f * u;     hnext = st + dt * 0.5f * u; }
            else if (e == 2) { acc += 2.f * u;     hnext = st + dt * u;        }
            else             { acc += u; st += (dt / 6.0f) * acc; hnext = st;  }
            if (tid < 128) hin[hw] = hnext;
            __syncthreads();
        }
    }

    if (tid < 128) means[(s*NB + row)*NH + tid]        = st;
    else           logv[(s*NB + row)*NH + (tid - 128)] = st;
}

// ---------------------------------------------------------------------------
// Kernel 3: fusion (attention over scales) + 48-step GRU decoder.
// One block per batch row (256 blocks x 384 threads). whh row in registers.
// ---------------------------------------------------------------------------
__global__ __launch_bounds__(384, 1) void k_gru(
    const float* __restrict__ means, const float* __restrict__ logvars,
    const float* __restrict__ a1w, const float* __restrict__ a1b,
    const float* __restrict__ a2w, const float* __restrict__ a2b,
    const float* __restrict__ wih, const float* __restrict__ whh,
    const float* __restrict__ bih, const float* __restrict__ bhh,
    const float* __restrict__ fcw, const float* __restrict__ fcb,
    const float* __restrict__ lvw, const float* __restrict__ lvb,
    const float* __restrict__ init_token, float* __restrict__ out)
{
    const int b   = blockIdx.x;
    const int tid = threadIdx.x;

    __shared__ __align__(16) float msh[4][128];
    __shared__ __align__(16) float hl[128];
    __shared__ float ghl[384];
    __shared__ float scoreL[4];
    __shared__ float unc_part[2][4];
    __shared__ float wgt[4];
    __shared__ float redL[2][2];
    __shared__ float tokL;

    for (int e = tid; e < 512; e += 384) {
        int s = e >> 7, i = e & 127;
        msh[s][i] = means[(s*NB + b)*NH + i];
    }
    __syncthreads();

    // uncertainty = mean(exp(logvar)) per scale
    if (tid < 128) {
        int wv = tid >> 6;
#pragma unroll
        for (int s = 0; s < 4; ++s) {
            float v = expf(logvars[(s*NB + b)*NH + tid]);
#pragma unroll
            for (int off = 32; off > 0; off >>= 1) v += __shfl_xor(v, off);
            if ((tid & 63) == 0) unc_part[wv][s] = v;
        }
    }
    // attention scores: relu(means @ a1w + a1b) @ a2w + a2b
    if (tid < 128) {
        int s = tid >> 5, a = tid & 31;
        float hd = a1b[a];
#pragma unroll 4
        for (int i = 0; i < 128; ++i) hd += msh[s][i] * a1w[i*32 + a];
        hd = fmaxf(hd, 0.f);
        float sc = hd * a2w[a];
#pragma unroll
        for (int off = 16; off > 0; off >>= 1) sc += __shfl_xor(sc, off);
        if (a == 0) scoreL[s] = sc + a2b[0];
    }
    __syncthreads();
    if (tid == 0) {
        float sv[4], mx = -1e30f;
#pragma unroll
        for (int s = 0; s < 4; ++s) {
            float u = (unc_part[0][s] + unc_part[1][s]) / 128.f;
            sv[s] = scoreL[s] / (u + 1e-6f);
            mx = fmaxf(mx, sv[s]);
        }
        float se = 0.f, ev[4];
#pragma unroll
        for (int s = 0; s < 4; ++s) { ev[s] = expf(sv[s] - mx); se += ev[s]; }
#pragma unroll
        for (int s = 0; s < 4; ++s) wgt[s] = ev[s] / se;
        tokL = init_token[0];
    }
    __syncthreads();
    if (tid < 128) {
        float f = 0.f;
#pragma unroll
        for (int s = 0; s < 4; ++s) f += wgt[s] * msh[s][tid];
        hl[tid] = f;
    }

    // register-resident GRU weights
    float4 whh4[32];
    const float4* wr = (const float4*)(whh + tid*128);
#pragma unroll
    for (int k = 0; k < 32; ++k) whh4[k] = wr[k];
    float bhhj = bhh[tid];
    float wih_r = 0.f, wih_z = 0.f, wih_n = 0.f;
    float bih_r = 0.f, bih_z = 0.f, bih_n = 0.f;
    float fcwi = 0.f, lvwi = 0.f;
    if (tid < 128) {
        wih_r = wih[tid]; wih_z = wih[128+tid]; wih_n = wih[256+tid];
        bih_r = bih[tid]; bih_z = bih[128+tid]; bih_n = bih[256+tid];
        fcwi  = fcw[tid]; lvwi  = lvw[tid];
    }
    const float fcbv = fcb[0], lvbv = lvb[0];
    __syncthreads();

    for (int t = 0; t < NFH; ++t) {
        float g0 = 0.f, g1 = 0.f, g2 = 0.f, g3 = 0.f;
        const float4* h4 = (const float4*)hl;
#pragma unroll
        for (int k = 0; k < 32; ++k) {
            float4 hv = h4[k];
            float4 wvv = whh4[k];
            g0 += hv.x * wvv.x; g1 += hv.y * wvv.y;
            g2 += hv.z * wvv.z; g3 += hv.w * wvv.w;
        }
        ghl[tid] = ((g0 + g1) + (g2 + g3)) + bhhj;
        __syncthreads();

        if (tid < 128) {
            float tok = tokL;
            float r  = 1.f / (1.f + expf(-(tok*wih_r + bih_r + ghl[tid])));
            float zz = 1.f / (1.f + expf(-(tok*wih_z + bih_z + ghl[128+tid])));
            float n  = tanhf(tok*wih_n + bih_n + r * ghl[256+tid]);
            float hn = (1.f - zz) * n + zz * hl[tid];
            hl[tid] = hn;
            float pp = hn * fcwi, pl = hn * lvwi;
#pragma unroll
            for (int off = 32; off > 0; off >>= 1) {
                pp += __shfl_xor(pp, off);
                pl += __shfl_xor(pl, off);
            }
            int wvx = tid >> 6;
            if ((tid & 63) == 0) { redL[wvx][0] = pp; redL[wvx][1] = pl; }
        }
        __syncthreads();
        if (tid == 0) {
            float pr = redL[0][0] + redL[1][0] + fcbv;
            float pv = redL[0][1] + redL[1][1] + lvbv;
            out[b*NFH + t] = pr;
            out[NB*NFH + b*NFH + t] = pv;
            tokL = pr;
        }
        __syncthreads();
    }
}

// ---------------------------------------------------------------------------
extern "C" void kernel_launch(void* const* d_in, const int* in_sizes, int n_in,
                              void* d_out, int out_size, void* d_ws, size_t ws_size,
                              hipStream_t stream)
{
    const float* x      = (const float*)d_in[0];
    const float* tspan  = (const float*)d_in[1];
    const float* c1w    = (const float*)d_in[2];
    const float* c1b    = (const float*)d_in[3];
    const float* bn1g   = (const float*)d_in[4];
    const float* bn1b   = (const float*)d_in[5];
    const float* c2w    = (const float*)d_in[6];
    const float* c2b    = (const float*)d_in[7];
    const float* bn2g   = (const float*)d_in[8];
    const float* bn2b   = (const float*)d_in[9];
    const float* dw1    = (const float*)d_in[10];
    const float* db1    = (const float*)d_in[11];
    const float* dw2    = (const float*)d_in[12];
    const float* db2    = (const float*)d_in[13];
    const float* a1w    = (const float*)d_in[14];
    const float* a1b    = (const float*)d_in[15];
    const float* a2w    = (const float*)d_in[16];
    const float* a2b    = (const float*)d_in[17];
    const float* wih    = (const float*)d_in[18];
    const float* whh    = (const float*)d_in[19];
    const float* bih    = (const float*)d_in[20];
    const float* bhh    = (const float*)d_in[21];
    const float* fcw    = (const float*)d_in[22];
    const float* fcb    = (const float*)d_in[23];
    const float* lvw    = (const float*)d_in[24];
    const float* lvb    = (const float*)d_in[25];
    const float* itok   = (const float*)d_in[26];

    float* ws    = (float*)d_ws;
    float* xseq  = ws;                 // 4*256*256      = 262144
    float* tmpA  = ws + 262144;        // 262144 (decompose scratch; its head
                                       //         is reused as imid after)
    float* tmpB  = ws + 524288;        // 262144
    float* means = ws + 786432;        // 131072
    float* logv  = ws + 917504;        // 131072
    int*   imid  = (int*)tmpA;         // 255 ints, written AFTER decompose done

    k_decompose<<<4, 1024, 0, stream>>>(x, c1w, c1b, bn1g, bn1b,
                                        c2w, c2b, bn2g, bn2b,
                                        tmpA, tmpB, xseq);
    k_prep<<<1, 256, 0, stream>>>(tspan, imid);
    k_ode<<<1024, 256, 0, stream>>>(xseq, tspan, imid, dw1, db1, dw2, db2,
                                    means, logv);
    k_gru<<<256, 384, 0, stream>>>(means, logv, a1w, a1b, a2w, a2b,
                                   wih, whh, bih, bhh, fcw, fcb, lvw, lvb,
                                   itok, (float*)d_out);
}

// Round 4
// 497.780 us; speedup vs baseline: 4.6785x; 2.2691x over previous
//
#include <hip/hip_runtime.h>
#include <math.h>

#define NS   4
#define NB   256
#define NT   256
#define NH   128
#define NDW  64
#define NFH  48

// ---------------------------------------------------------------------------
// Kernel 1: multi-scale decompose: conv1d(K=5,pad=2) -> BN -> relu, twice.
// One block per scale (4 blocks x 1024 threads). BN stats in f64.
// ---------------------------------------------------------------------------
__global__ __launch_bounds__(1024) void k_decompose(
    const float* __restrict__ x,
    const float* __restrict__ c1w, const float* __restrict__ c1b,
    const float* __restrict__ g1,  const float* __restrict__ b1,
    const float* __restrict__ c2w, const float* __restrict__ c2b,
    const float* __restrict__ g2,  const float* __restrict__ b2,
    float* __restrict__ tmpA, float* __restrict__ tmpB, float* __restrict__ xseq)
{
    const int s   = blockIdx.x;
    const int tid = threadIdx.x;
    const int N   = NB * NT;
    __shared__ double redS[1024];
    __shared__ double redQ[1024];
    __shared__ float  statf[2];

    float w[5];
#pragma unroll
    for (int k = 0; k < 5; ++k) w[k] = c1w[s*5 + k];
    float cb = c1b[s];
    double ls = 0.0, lq = 0.0;
    for (int e = tid; e < N; e += 1024) {
        int bb = e >> 8, t = e & 255;
        const float* xb = x + bb * NT;
        float acc = cb;
#pragma unroll
        for (int k = 0; k < 5; ++k) {
            int tt = t + k - 2;
            if (tt >= 0 && tt < NT) acc += xb[tt] * w[k];
        }
        tmpA[s*N + e] = acc;
        ls += (double)acc; lq += (double)acc * (double)acc;
    }
    redS[tid] = ls; redQ[tid] = lq;
    __syncthreads();
    for (int off = 512; off > 0; off >>= 1) {
        if (tid < off) { redS[tid] += redS[tid+off]; redQ[tid] += redQ[tid+off]; }
        __syncthreads();
    }
    if (tid == 0) {
        double m = redS[0] / N;
        double v = redQ[0] / N - m*m;
        statf[0] = (float)m;
        statf[1] = (float)(1.0 / sqrt(v + 1e-5));
    }
    __syncthreads();
    {
        float m1 = statf[0], is1 = statf[1], gg = g1[s], bo = b1[s];
        for (int e = tid; e < N; e += 1024) {
            float y  = tmpA[s*N + e];
            float hn = gg * (y - m1) * is1 + bo;
            tmpB[s*N + e] = fmaxf(hn, 0.f);
        }
    }
    __syncthreads();
    // stage 2
#pragma unroll
    for (int k = 0; k < 5; ++k) w[k] = c2w[s*5 + k];
    cb = c2b[s];
    ls = 0.0; lq = 0.0;
    for (int e = tid; e < N; e += 1024) {
        int bb = e >> 8, t = e & 255;
        const float* hb = tmpB + s*N + bb*NT;
        float acc = cb;
#pragma unroll
        for (int k = 0; k < 5; ++k) {
            int tt = t + k - 2;
            if (tt >= 0 && tt < NT) acc += hb[tt] * w[k];
        }
        tmpA[s*N + e] = acc;
        ls += (double)acc; lq += (double)acc * (double)acc;
    }
    redS[tid] = ls; redQ[tid] = lq;
    __syncthreads();
    for (int off = 512; off > 0; off >>= 1) {
        if (tid < off) { redS[tid] += redS[tid+off]; redQ[tid] += redQ[tid+off]; }
        __syncthreads();
    }
    if (tid == 0) {
        double m = redS[0] / N;
        double v = redQ[0] / N - m*m;
        statf[0] = (float)m;
        statf[1] = (float)(1.0 / sqrt(v + 1e-5));
    }
    __syncthreads();
    {
        float m2 = statf[0], is2 = statf[1], gg = g2[s], bo = b2[s];
        for (int e = tid; e < N; e += 1024) {
            float y  = tmpA[s*N + e];
            float hn = gg * (y - m2) * is2 + bo;
            xseq[s*N + e] = fmaxf(hn, 0.f);
        }
    }
}

// ---------------------------------------------------------------------------
// Kernel 1b: precompute the JAX argmin(|t_span - tm|) midpoint index table
// (identical f32 ops, first-min-wins).
// ---------------------------------------------------------------------------
__global__ void k_prep(const float* __restrict__ tspan, int* __restrict__ imid_g)
{
    __shared__ float ts[256];
    const int tid = threadIdx.x;
    ts[tid] = tspan[tid];
    __syncthreads();
    if (tid < 255) {
        float t0 = ts[tid], t1 = ts[tid+1];
        float tm = t0 + (t1 - t0) * 0.5f;
        int best = 0; float bd = fabsf(ts[0] - tm);
        for (int j = 1; j < 256; ++j) {
            float d = fabsf(ts[j] - tm);
            if (d < bd) { bd = d; best = j; }
        }
        imid_g[tid] = best;
    }
}

// ---------------------------------------------------------------------------
// Kernel 1c: precompute the collapsed ODE operator per scale:
//   Mt[s][c][k] = sum_j W2[k][j] * W1[j][c]   (j < 128, f64 accumulate)
//   bM[s][c]    = sum_j b2[j]    * W1[j][c]
//   Tg          = sum_i (tspan[i+1]-tspan[i])   (f32, reference order)
// The RK4 recursion is linear in u1 after the relu, so the 128-dim h state
// can be tracked as a = W1h^T h (64-dim) with update a += c*dt*(M u1 + bM).
// ---------------------------------------------------------------------------
__global__ __launch_bounds__(256) void k_mat(
    const float* __restrict__ dw1, const float* __restrict__ dw2,
    const float* __restrict__ db2, const float* __restrict__ tspan,
    float* __restrict__ Mt, float* __restrict__ bM, float* __restrict__ Tg)
{
    const int s   = blockIdx.x;
    const int tid = threadIdx.x;
    for (int e = tid; e < 4096; e += 256) {
        int c = e >> 6, k = e & 63;
        double acc = 0.0;
        for (int j = 0; j < 128; ++j)
            acc += (double)dw2[(s*64 + k)*256 + j] * (double)dw1[(s*130 + j)*64 + c];
        Mt[(s*64 + c)*64 + k] = (float)acc;
    }
    if (tid < 64) {
        double acc = 0.0;
        for (int j = 0; j < 128; ++j)
            acc += (double)db2[s*256 + j] * (double)dw1[(s*130 + j)*64 + tid];
        bM[s*64 + tid] = (float)acc;
    }
    if (s == 0 && tid == 0) {
        float T = 0.f;
        for (int i = 0; i < 255; ++i) T += (tspan[i+1] - tspan[i]);
        Tg[0] = T;
    }
}

// ---------------------------------------------------------------------------
// Kernel 2: RK4 scan in the collapsed 64-dim space. 1024 blocks x 64 threads
// (1 wave per (scale,row)). Everything register-resident: M column (64),
// t_span/x_row/imid lane-distributed (4 regs each), state a[c], S[c].
// u1 broadcast via v_readlane + scalar-operand FMA. NO LDS, NO barriers.
// ---------------------------------------------------------------------------
__device__ __forceinline__ float rlf(float v, int l) {
    return __int_as_float(__builtin_amdgcn_readlane(__float_as_int(v), l));
}
__device__ __forceinline__ float pick4f(float r0, float r1, float r2, float r3, int i) {
    int l = i & 63, h = i >> 6;
    float a = (h & 2) ? ((h & 1) ? r3 : r2) : ((h & 1) ? r1 : r0);
    return rlf(a, l);
}
__device__ __forceinline__ int pick4i(int r0, int r1, int r2, int r3, int i) {
    int l = i & 63, h = i >> 6;
    int a = (h & 2) ? ((h & 1) ? r3 : r2) : ((h & 1) ? r1 : r0);
    return __builtin_amdgcn_readlane(a, l);
}
__device__ __forceinline__ float dot64(float u1, const float* Mc, float bMc) {
    float d0 = bMc, d1 = 0.f, d2 = 0.f, d3 = 0.f;
#pragma unroll
    for (int k = 0; k < 64; k += 4) {
        d0 = fmaf(rlf(u1, k+0), Mc[k+0], d0);
        d1 = fmaf(rlf(u1, k+1), Mc[k+1], d1);
        d2 = fmaf(rlf(u1, k+2), Mc[k+2], d2);
        d3 = fmaf(rlf(u1, k+3), Mc[k+3], d3);
    }
    return (d0 + d1) + (d2 + d3);
}

__global__ __attribute__((amdgpu_waves_per_eu(1, 1)))
__launch_bounds__(64) void k_ode(
    const float* __restrict__ xseq, const float* __restrict__ tspan,
    const int*   __restrict__ imid_g,
    const float* __restrict__ Mt, const float* __restrict__ bM_g,
    const float* __restrict__ dw1, const float* __restrict__ db1,
    float* __restrict__ S_g)
{
    const int b   = blockIdx.x;
    const int s   = b >> 8;
    const int row = b & 255;
    const int c   = threadIdx.x;            // 0..63: this lane's column

    const float* __restrict__ xrow = xseq + (s*NB + row)*NT;

    // lane-distributed tables (no in-loop memory)
    float ts0 = tspan[c],       ts1 = tspan[64 + c];
    float ts2 = tspan[128 + c], ts3 = tspan[192 + c];
    float xr0 = xrow[c],        xr1 = xrow[64 + c];
    float xr2 = xrow[128 + c],  xr3 = xrow[192 + c];
    int   im0 = imid_g[c];
    int   im1 = imid_g[64 + c];
    int   im2 = imid_g[128 + c];
    int   im3 = (192 + c < 255) ? imid_g[192 + c] : 0;

    // per-column constants
    const float bMc = bM_g[s*64 + c];
    const float b1c = db1[s*64 + c];
    const float w1x = dw1[(s*130 + 128)*64 + c];
    const float w1t = dw1[(s*130 + 129)*64 + c];

    // M column (this lane's 64 coefficients), register-resident
    float Mc[64];
    const float4* mp = (const float4*)(Mt + (s*64 + c)*64);
#pragma unroll
    for (int j = 0; j < 16; ++j) {
        float4 t = mp[j];
        Mc[4*j+0] = t.x; Mc[4*j+1] = t.y; Mc[4*j+2] = t.z; Mc[4*j+3] = t.w;
    }
#pragma unroll
    for (int j = 0; j < 64; ++j) asm volatile("" : "+v"(Mc[j]));

    float a = 0.f;   // a[c] = (W1h^T h)[c]
    float S = 0.f;   // S[c] = sum_i dt/6 (u11+2u12+2u13+u14)[c]

    for (int i = 0; i < 255; ++i) {
        float t0 = pick4f(ts0, ts1, ts2, ts3, i);
        float t1 = pick4f(ts0, ts1, ts2, ts3, i + 1);
        float dt = t1 - t0;
        int   im = pick4i(im0, im1, im2, im3, i);
        float xi = pick4f(xr0, xr1, xr2, xr3, i);
        float xm = pick4f(xr0, xr1, xr2, xr3, im);
        float x1 = pick4f(xr0, xr1, xr2, xr3, i + 1);
        float tm = t0 + dt * 0.5f;
        float hdt = dt * 0.5f;

        float u11 = fmaxf(a + b1c + xi*w1x + t0*w1t, 0.f);
        float v1  = dot64(u11, Mc, bMc);
        float u12 = fmaxf(fmaf(hdt, v1, a) + b1c + xm*w1x + tm*w1t, 0.f);
        float v2  = dot64(u12, Mc, bMc);
        float u13 = fmaxf(fmaf(hdt, v2, a) + b1c + xm*w1x + tm*w1t, 0.f);
        float v3  = dot64(u13, Mc, bMc);
        float u14 = fmaxf(fmaf(dt, v3, a) + b1c + x1*w1x + t1*w1t, 0.f);
        float v4  = dot64(u14, Mc, bMc);

        float d6 = dt * (1.0f / 6.0f);
        a += d6 * ((v1 + v4) + 2.f*(v2 + v3));
        S += d6 * ((u11 + u14) + 2.f*(u12 + u13));
    }

    S_g[(s*256 + row)*64 + c] = S;
}

// ---------------------------------------------------------------------------
// Kernel 2b: reconstruct means/logvars from S:  out[j] = (W2^T S)[j] + T*b2[j]
// 1024 blocks x 256 threads; block = (s,row), thread = output column.
// ---------------------------------------------------------------------------
__global__ __launch_bounds__(256) void k_recon(
    const float* __restrict__ S_g, const float* __restrict__ dw2,
    const float* __restrict__ db2, const float* __restrict__ Tg,
    float* __restrict__ means, float* __restrict__ logv)
{
    const int b   = blockIdx.x;
    const int s   = b >> 8;
    const int row = b & 255;
    const int j   = threadIdx.x;
    __shared__ __align__(16) float Ssh[64];
    if (j < 64) Ssh[j] = S_g[(s*256 + row)*64 + j];
    __syncthreads();
    float acc = Tg[0] * db2[s*256 + j];
    const float4* s4 = (const float4*)Ssh;
#pragma unroll
    for (int k4 = 0; k4 < 16; ++k4) {
        float4 sv = s4[k4];
        acc += sv.x * dw2[(s*64 + 4*k4 + 0)*256 + j]
             + sv.y * dw2[(s*64 + 4*k4 + 1)*256 + j]
             + sv.z * dw2[(s*64 + 4*k4 + 2)*256 + j]
             + sv.w * dw2[(s*64 + 4*k4 + 3)*256 + j];
    }
    if (j < 128) means[(s*NB + row)*NH + j]        = acc;
    else         logv[(s*NB + row)*NH + (j - 128)] = acc;
}

// ---------------------------------------------------------------------------
// Kernel 3: fusion (attention over scales) + 48-step GRU decoder.
// One block per batch row (256 blocks x 384 threads). whh row in registers.
// ---------------------------------------------------------------------------
__global__ __launch_bounds__(384, 1) void k_gru(
    const float* __restrict__ means, const float* __restrict__ logvars,
    const float* __restrict__ a1w, const float* __restrict__ a1b,
    const float* __restrict__ a2w, const float* __restrict__ a2b,
    const float* __restrict__ wih, const float* __restrict__ whh,
    const float* __restrict__ bih, const float* __restrict__ bhh,
    const float* __restrict__ fcw, const float* __restrict__ fcb,
    const float* __restrict__ lvw, const float* __restrict__ lvb,
    const float* __restrict__ init_token, float* __restrict__ out)
{
    const int b   = blockIdx.x;
    const int tid = threadIdx.x;

    __shared__ __align__(16) float msh[4][128];
    __shared__ __align__(16) float hl[128];
    __shared__ float ghl[384];
    __shared__ float scoreL[4];
    __shared__ float unc_part[2][4];
    __shared__ float wgt[4];
    __shared__ float redL[2][2];
    __shared__ float tokL;

    for (int e = tid; e < 512; e += 384) {
        int s = e >> 7, i = e & 127;
        msh[s][i] = means[(s*NB + b)*NH + i];
    }
    __syncthreads();

    // uncertainty = mean(exp(logvar)) per scale
    if (tid < 128) {
        int wv = tid >> 6;
#pragma unroll
        for (int s = 0; s < 4; ++s) {
            float v = expf(logvars[(s*NB + b)*NH + tid]);
#pragma unroll
            for (int off = 32; off > 0; off >>= 1) v += __shfl_xor(v, off);
            if ((tid & 63) == 0) unc_part[wv][s] = v;
        }
    }
    // attention scores: relu(means @ a1w + a1b) @ a2w + a2b
    if (tid < 128) {
        int s = tid >> 5, a = tid & 31;
        float hd = a1b[a];
#pragma unroll 4
        for (int i = 0; i < 128; ++i) hd += msh[s][i] * a1w[i*32 + a];
        hd = fmaxf(hd, 0.f);
        float sc = hd * a2w[a];
#pragma unroll
        for (int off = 16; off > 0; off >>= 1) sc += __shfl_xor(sc, off);
        if (a == 0) scoreL[s] = sc + a2b[0];
    }
    __syncthreads();
    if (tid == 0) {
        float sv[4], mx = -1e30f;
#pragma unroll
        for (int s = 0; s < 4; ++s) {
            float u = (unc_part[0][s] + unc_part[1][s]) / 128.f;
            sv[s] = scoreL[s] / (u + 1e-6f);
            mx = fmaxf(mx, sv[s]);
        }
        float se = 0.f, ev[4];
#pragma unroll
        for (int s = 0; s < 4; ++s) { ev[s] = expf(sv[s] - mx); se += ev[s]; }
#pragma unroll
        for (int s = 0; s < 4; ++s) wgt[s] = ev[s] / se;
        tokL = init_token[0];
    }
    __syncthreads();
    if (tid < 128) {
        float f = 0.f;
#pragma unroll
        for (int s = 0; s < 4; ++s) f += wgt[s] * msh[s][tid];
        hl[tid] = f;
    }

    // register-resident GRU weights
    float4 whh4[32];
    const float4* wr = (const float4*)(whh + tid*128);
#pragma unroll
    for (int k = 0; k < 32; ++k) whh4[k] = wr[k];
    float bhhj = bhh[tid];
    float wih_r = 0.f, wih_z = 0.f, wih_n = 0.f;
    float bih_r = 0.f, bih_z = 0.f, bih_n = 0.f;
    float fcwi = 0.f, lvwi = 0.f;
    if (tid < 128) {
        wih_r = wih[tid]; wih_z = wih[128+tid]; wih_n = wih[256+tid];
        bih_r = bih[tid]; bih_z = bih[128+tid]; bih_n = bih[256+tid];
        fcwi  = fcw[tid]; lvwi  = lvw[tid];
    }
    const float fcbv = fcb[0], lvbv = lvb[0];
    __syncthreads();

    for (int t = 0; t < NFH; ++t) {
        float g0 = 0.f, g1 = 0.f, g2 = 0.f, g3 = 0.f;
        const float4* h4 = (const float4*)hl;
#pragma unroll
        for (int k = 0; k < 32; ++k) {
            float4 hv = h4[k];
            float4 wvv = whh4[k];
            g0 += hv.x * wvv.x; g1 += hv.y * wvv.y;
            g2 += hv.z * wvv.z; g3 += hv.w * wvv.w;
        }
        ghl[tid] = ((g0 + g1) + (g2 + g3)) + bhhj;
        __syncthreads();

        if (tid < 128) {
            float tok = tokL;
            float r  = 1.f / (1.f + expf(-(tok*wih_r + bih_r + ghl[tid])));
            float zz = 1.f / (1.f + expf(-(tok*wih_z + bih_z + ghl[128+tid])));
            float n  = tanhf(tok*wih_n + bih_n + r * ghl[256+tid]);
            float hn = (1.f - zz) * n + zz * hl[tid];
            hl[tid] = hn;
            float pp = hn * fcwi, pl = hn * lvwi;
#pragma unroll
            for (int off = 32; off > 0; off >>= 1) {
                pp += __shfl_xor(pp, off);
                pl += __shfl_xor(pl, off);
            }
            int wvx = tid >> 6;
            if ((tid & 63) == 0) { redL[wvx][0] = pp; redL[wvx][1] = pl; }
        }
        __syncthreads();
        if (tid == 0) {
            float pr = redL[0][0] + redL[1][0] + fcbv;
            float pv = redL[0][1] + redL[1][1] + lvbv;
            out[b*NFH + t] = pr;
            out[NB*NFH + b*NFH + t] = pv;
            tokL = pr;
        }
        __syncthreads();
    }
}

// ---------------------------------------------------------------------------
extern "C" void kernel_launch(void* const* d_in, const int* in_sizes, int n_in,
                              void* d_out, int out_size, void* d_ws, size_t ws_size,
                              hipStream_t stream)
{
    const float* x      = (const float*)d_in[0];
    const float* tspan  = (const float*)d_in[1];
    const float* c1w    = (const float*)d_in[2];
    const float* c1b    = (const float*)d_in[3];
    const float* bn1g   = (const float*)d_in[4];
    const float* bn1b   = (const float*)d_in[5];
    const float* c2w    = (const float*)d_in[6];
    const float* c2b    = (const float*)d_in[7];
    const float* bn2g   = (const float*)d_in[8];
    const float* bn2b   = (const float*)d_in[9];
    const float* dw1    = (const float*)d_in[10];
    const float* db1    = (const float*)d_in[11];
    const float* dw2    = (const float*)d_in[12];
    const float* db2    = (const float*)d_in[13];
    const float* a1w    = (const float*)d_in[14];
    const float* a1b    = (const float*)d_in[15];
    const float* a2w    = (const float*)d_in[16];
    const float* a2b    = (const float*)d_in[17];
    const float* wih    = (const float*)d_in[18];
    const float* whh    = (const float*)d_in[19];
    const float* bih    = (const float*)d_in[20];
    const float* bhh    = (const float*)d_in[21];
    const float* fcw    = (const float*)d_in[22];
    const float* fcb    = (const float*)d_in[23];
    const float* lvw    = (const float*)d_in[24];
    const float* lvb    = (const float*)d_in[25];
    const float* itok   = (const float*)d_in[26];

    float* ws    = (float*)d_ws;
    float* xseq  = ws;                 // [0, 262144)
    float* tmpA  = ws + 262144;        // decompose scratch; head reused as imid
    float* tmpB  = ws + 524288;        // decompose scratch; reused below
    float* means = ws + 786432;        // 131072
    float* logv  = ws + 917504;        // 131072
    int*   imid  = (int*)tmpA;         // 255 ints (after decompose)
    float* S_g   = tmpB;               // 65536 floats (after decompose)
    float* Mt    = ws + 589824;        // 16384
    float* bMg   = ws + 606208;        // 256
    float* Tg    = ws + 606464;        // 1

    k_decompose<<<4, 1024, 0, stream>>>(x, c1w, c1b, bn1g, bn1b,
                                        c2w, c2b, bn2g, bn2b,
                                        tmpA, tmpB, xseq);
    k_prep<<<1, 256, 0, stream>>>(tspan, imid);
    k_mat<<<4, 256, 0, stream>>>(dw1, dw2, db2, tspan, Mt, bMg, Tg);
    k_ode<<<1024, 64, 0, stream>>>(xseq, tspan, imid, Mt, bMg, dw1, db1, S_g);
    k_recon<<<1024, 256, 0, stream>>>(S_g, dw2, db2, Tg, means, logv);
    k_gru<<<256, 384, 0, stream>>>(means, logv, a1w, a1b, a2w, a2b,
                                   wih, whh, bih, bhh, fcw, fcb, lvw, lvb,
                                   itok, (float*)d_out);
}

// Round 5
// 366.606 us; speedup vs baseline: 6.3525x; 1.3578x over previous
//
#include <hip/hip_runtime.h>
#include <math.h>

#define NS   4
#define NB   256
#define NT   256
#define NH   128
#define NDW  64
#define NFH  48

// ===========================================================================
// Decompose pipeline (replaces the old 4-block monolith):
//  k_d1 : conv1 + f64 partial stats          (64 blocks = (s,chunk) x 256 thr)
//  k_d2 : finalize stats1 + imid table + Tg  (1 block)
//  k_d3 : bn1+relu (LDS row) + conv2 + f64 partial stats   (64 blocks)
//  k_d4 : finalize stats2                    (1 block)
// conv2's BN affine + relu is applied INSIDE k_ode's x-load (saves a pass).
// ===========================================================================
__global__ __launch_bounds__(256) void k_d1(
    const float* __restrict__ x,
    const float* __restrict__ c1w, const float* __restrict__ c1b,
    float* __restrict__ tmpA, double* __restrict__ pp1)
{
    const int s     = blockIdx.x >> 4;
    const int chunk = blockIdx.x & 15;
    const int tid   = threadIdx.x;
    __shared__ double wred[4][2];

    float w[5];
#pragma unroll
    for (int k = 0; k < 5; ++k) w[k] = c1w[s*5 + k];
    const float cb = c1b[s];

    double ls = 0.0, lq = 0.0;
#pragma unroll 4
    for (int r = 0; r < 16; ++r) {
        const int bb = chunk*16 + r;
        const float* xb = x + bb*NT;
        float acc = cb;
#pragma unroll
        for (int k = 0; k < 5; ++k) {
            int tt = tid + k - 2;
            if (tt >= 0 && tt < NT) acc += xb[tt] * w[k];
        }
        tmpA[s*65536 + bb*NT + tid] = acc;
        ls += (double)acc; lq += (double)acc * (double)acc;
    }
#pragma unroll
    for (int off = 32; off > 0; off >>= 1) {
        ls += __shfl_xor(ls, off); lq += __shfl_xor(lq, off);
    }
    if ((tid & 63) == 0) { wred[tid>>6][0] = ls; wred[tid>>6][1] = lq; }
    __syncthreads();
    if (tid == 0) {
        pp1[(s*16 + chunk)*2 + 0] = wred[0][0]+wred[1][0]+wred[2][0]+wred[3][0];
        pp1[(s*16 + chunk)*2 + 1] = wred[0][1]+wred[1][1]+wred[2][1]+wred[3][1];
    }
}

__global__ __launch_bounds__(256) void k_d2(
    const float* __restrict__ tspan, const double* __restrict__ pp1,
    float* __restrict__ st1, int* __restrict__ imid_g, float* __restrict__ Tg)
{
    const int tid = threadIdx.x;
    __shared__ float ts[256];
    ts[tid] = tspan[tid];
    __syncthreads();
    if (tid < 255) {
        float t0 = ts[tid], t1 = ts[tid+1];
        float tm = t0 + (t1 - t0) * 0.5f;
        int best = 0; float bd = fabsf(ts[0] - tm);
        for (int j = 1; j < 256; ++j) {
            float d = fabsf(ts[j] - tm);
            if (d < bd) { bd = d; best = j; }
        }
        imid_g[tid] = best;
    }
    if (tid < 4) {
        double lsum = 0.0, lsq = 0.0;
        for (int cch = 0; cch < 16; ++cch) {
            lsum += pp1[(tid*16 + cch)*2 + 0];
            lsq  += pp1[(tid*16 + cch)*2 + 1];
        }
        const double N = 65536.0;
        double m = lsum / N;
        double v = lsq / N - m*m;
        st1[tid*2 + 0] = (float)m;
        st1[tid*2 + 1] = (float)(1.0 / sqrt(v + 1e-5));
    }
    if (tid == 4) {
        float T = 0.f;
        for (int i = 0; i < 255; ++i) T += (ts[i+1] - ts[i]);
        Tg[0] = T;
    }
}

__global__ __launch_bounds__(256) void k_d3(
    const float* __restrict__ tmpA, const float* __restrict__ st1,
    const float* __restrict__ g1,  const float* __restrict__ b1,
    const float* __restrict__ c2w, const float* __restrict__ c2b,
    float* __restrict__ cv2, double* __restrict__ pp2)
{
    const int s     = blockIdx.x >> 4;
    const int chunk = blockIdx.x & 15;
    const int tid   = threadIdx.x;
    __shared__ float hsh[256];
    __shared__ double wred[4][2];

    const float m1 = st1[s*2+0], rs1 = st1[s*2+1];
    const float A1 = g1[s]*rs1,  B1  = b1[s] - g1[s]*m1*rs1;
    float w[5];
#pragma unroll
    for (int k = 0; k < 5; ++k) w[k] = c2w[s*5 + k];
    const float cb = c2b[s];

    double ls = 0.0, lq = 0.0;
    for (int r = 0; r < 16; ++r) {
        const int bb = chunk*16 + r;
        float y = tmpA[s*65536 + bb*NT + tid];
        hsh[tid] = fmaxf(fmaf(A1, y, B1), 0.f);
        __syncthreads();
        float acc = cb;
#pragma unroll
        for (int k = 0; k < 5; ++k) {
            int tt = tid + k - 2;
            if (tt >= 0 && tt < NT) acc += hsh[tt] * w[k];
        }
        cv2[s*65536 + bb*NT + tid] = acc;
        ls += (double)acc; lq += (double)acc * (double)acc;
        __syncthreads();
    }
#pragma unroll
    for (int off = 32; off > 0; off >>= 1) {
        ls += __shfl_xor(ls, off); lq += __shfl_xor(lq, off);
    }
    if ((tid & 63) == 0) { wred[tid>>6][0] = ls; wred[tid>>6][1] = lq; }
    __syncthreads();
    if (tid == 0) {
        pp2[(s*16 + chunk)*2 + 0] = wred[0][0]+wred[1][0]+wred[2][0]+wred[3][0];
        pp2[(s*16 + chunk)*2 + 1] = wred[0][1]+wred[1][1]+wred[2][1]+wred[3][1];
    }
}

__global__ __launch_bounds__(64) void k_d4(
    const double* __restrict__ pp2, float* __restrict__ st2)
{
    const int tid = threadIdx.x;
    if (tid < 4) {
        double lsum = 0.0, lsq = 0.0;
        for (int cch = 0; cch < 16; ++cch) {
            lsum += pp2[(tid*16 + cch)*2 + 0];
            lsq  += pp2[(tid*16 + cch)*2 + 1];
        }
        const double N = 65536.0;
        double m = lsum / N;
        double v = lsq / N - m*m;
        st2[tid*2 + 0] = (float)m;
        st2[tid*2 + 1] = (float)(1.0 / sqrt(v + 1e-5));
    }
}

// ---------------------------------------------------------------------------
// k_mat: collapsed operator  Mt[s][c][k] = sum_{j<128} W2[k][j] W1[j][c] (f64)
//        bM[s][c] = sum_{j<128} b2[j] W1[j][c]
// 256 blocks = (s,c), 64 threads = k. dw1 column staged in LDS; dw2 row read
// as coalesced float4.
// ---------------------------------------------------------------------------
__global__ __launch_bounds__(64) void k_mat(
    const float* __restrict__ dw1, const float* __restrict__ dw2,
    const float* __restrict__ db2,
    float* __restrict__ Mt, float* __restrict__ bM)
{
    const int s = blockIdx.x >> 6;
    const int c = blockIdx.x & 63;
    const int k = threadIdx.x;
    __shared__ float col[128];

    col[k]      = dw1[(s*130 + k)*64 + c];
    col[k + 64] = dw1[(s*130 + 64 + k)*64 + c];
    __syncthreads();

    const float4* dp = (const float4*)(dw2 + (s*64 + k)*256);
    double acc = 0.0;
#pragma unroll 8
    for (int j4 = 0; j4 < 32; ++j4) {
        float4 dv = dp[j4];
        acc += (double)dv.x * (double)col[4*j4+0]
             + (double)dv.y * (double)col[4*j4+1]
             + (double)dv.z * (double)col[4*j4+2]
             + (double)dv.w * (double)col[4*j4+3];
    }
    Mt[(s*64 + c)*64 + k] = (float)acc;

    double pb = (double)db2[s*256 + k]      * (double)col[k]
              + (double)db2[s*256 + 64 + k] * (double)col[k + 64];
#pragma unroll
    for (int off = 32; off > 0; off >>= 1) pb += __shfl_xor(pb, off);
    if (k == 0) bM[s*64 + c] = (float)pb;
}

// ---------------------------------------------------------------------------
// k_ode: RK4 scan in the collapsed 64-dim space. 1024 blocks x 64 threads.
// Software-pipelined readlane broadcast: prefetch the next 8-lane group
// while FMA-ing the current one (rl->use distance ~16 instrs).
// conv2's BN affine + relu applied on the x load (A2*raw + B2, clamped).
// ---------------------------------------------------------------------------
__device__ __forceinline__ float rlf(float v, int l) {
    return __int_as_float(__builtin_amdgcn_readlane(__float_as_int(v), l));
}
__device__ __forceinline__ float pick4f(float r0, float r1, float r2, float r3, int i) {
    int l = i & 63, h = i >> 6;
    float a = (h & 2) ? ((h & 1) ? r3 : r2) : ((h & 1) ? r1 : r0);
    return rlf(a, l);
}
__device__ __forceinline__ int pick4i(int r0, int r1, int r2, int r3, int i) {
    int l = i & 63, h = i >> 6;
    int a = (h & 2) ? ((h & 1) ? r3 : r2) : ((h & 1) ? r1 : r0);
    return __builtin_amdgcn_readlane(a, l);
}
__device__ __forceinline__ float dot64(float u1, const float* Mc, float bMc) {
    float d0 = bMc, d1 = 0.f, d2 = 0.f, d3 = 0.f;
    float cur[8], nxt[8];
#pragma unroll
    for (int k = 0; k < 8; ++k) cur[k] = rlf(u1, k);
#pragma unroll
    for (int g = 0; g < 8; ++g) {
        if (g < 7) {
#pragma unroll
            for (int k = 0; k < 8; ++k) nxt[k] = rlf(u1, 8*(g+1) + k);
        }
        d0 = fmaf(cur[0], Mc[8*g+0], d0);
        d1 = fmaf(cur[1], Mc[8*g+1], d1);
        d2 = fmaf(cur[2], Mc[8*g+2], d2);
        d3 = fmaf(cur[3], Mc[8*g+3], d3);
        d0 = fmaf(cur[4], Mc[8*g+4], d0);
        d1 = fmaf(cur[5], Mc[8*g+5], d1);
        d2 = fmaf(cur[6], Mc[8*g+6], d2);
        d3 = fmaf(cur[7], Mc[8*g+7], d3);
#pragma unroll
        for (int k = 0; k < 8; ++k) cur[k] = nxt[k];
    }
    return (d0 + d1) + (d2 + d3);
}

__global__ __attribute__((amdgpu_waves_per_eu(1, 1)))
__launch_bounds__(64) void k_ode(
    const float* __restrict__ cv2, const float* __restrict__ st2,
    const float* __restrict__ g2,  const float* __restrict__ b2,
    const float* __restrict__ tspan, const int* __restrict__ imid_g,
    const float* __restrict__ Mt, const float* __restrict__ bM_g,
    const float* __restrict__ dw1, const float* __restrict__ db1,
    float* __restrict__ S_g)
{
    const int b   = blockIdx.x;
    const int s   = b >> 8;
    const int row = b & 255;
    const int c   = threadIdx.x;

    // BN2 affine folded into the x load
    const float m2 = st2[s*2+0], rs2 = st2[s*2+1];
    const float A2 = g2[s]*rs2,  B2  = b2[s] - g2[s]*m2*rs2;

    const float* __restrict__ xrow = cv2 + (s*NB + row)*NT;

    float ts0 = tspan[c],       ts1 = tspan[64 + c];
    float ts2 = tspan[128 + c], ts3 = tspan[192 + c];
    float xr0 = fmaxf(fmaf(A2, xrow[c],       B2), 0.f);
    float xr1 = fmaxf(fmaf(A2, xrow[64 + c],  B2), 0.f);
    float xr2 = fmaxf(fmaf(A2, xrow[128 + c], B2), 0.f);
    float xr3 = fmaxf(fmaf(A2, xrow[192 + c], B2), 0.f);
    int   im0 = imid_g[c];
    int   im1 = imid_g[64 + c];
    int   im2 = imid_g[128 + c];
    int   im3 = (192 + c < 255) ? imid_g[192 + c] : 0;

    const float bMc = bM_g[s*64 + c];
    const float b1c = db1[s*64 + c];
    const float w1x = dw1[(s*130 + 128)*64 + c];
    const float w1t = dw1[(s*130 + 129)*64 + c];

    float Mc[64];
    const float4* mp = (const float4*)(Mt + (s*64 + c)*64);
#pragma unroll
    for (int j = 0; j < 16; ++j) {
        float4 t = mp[j];
        Mc[4*j+0] = t.x; Mc[4*j+1] = t.y; Mc[4*j+2] = t.z; Mc[4*j+3] = t.w;
    }
#pragma unroll
    for (int j = 0; j < 64; ++j) asm volatile("" : "+v"(Mc[j]));

    float a = 0.f;
    float S = 0.f;

    for (int i = 0; i < 255; ++i) {
        float t0 = pick4f(ts0, ts1, ts2, ts3, i);
        float t1 = pick4f(ts0, ts1, ts2, ts3, i + 1);
        float dt = t1 - t0;
        int   im = pick4i(im0, im1, im2, im3, i);
        float xi = pick4f(xr0, xr1, xr2, xr3, i);
        float xm = pick4f(xr0, xr1, xr2, xr3, im);
        float x1 = pick4f(xr0, xr1, xr2, xr3, i + 1);
        float tm = t0 + dt * 0.5f;
        float hdt = dt * 0.5f;

        float u11 = fmaxf(a + b1c + xi*w1x + t0*w1t, 0.f);
        float v1  = dot64(u11, Mc, bMc);
        float u12 = fmaxf(fmaf(hdt, v1, a) + b1c + xm*w1x + tm*w1t, 0.f);
        float v2  = dot64(u12, Mc, bMc);
        float u13 = fmaxf(fmaf(hdt, v2, a) + b1c + xm*w1x + tm*w1t, 0.f);
        float v3  = dot64(u13, Mc, bMc);
        float u14 = fmaxf(fmaf(dt, v3, a) + b1c + x1*w1x + t1*w1t, 0.f);
        float v4  = dot64(u14, Mc, bMc);

        float d6 = dt * (1.0f / 6.0f);
        a += d6 * ((v1 + v4) + 2.f*(v2 + v3));
        S += d6 * ((u11 + u14) + 2.f*(u12 + u13));
    }

    S_g[(s*256 + row)*64 + c] = S;
}

// ---------------------------------------------------------------------------
// k_gru: fused recon (S -> means, exp(logvar)) + attention fusion + 48-step
// GRU decoder. One block per batch row (256 blocks x 384 threads).
// ---------------------------------------------------------------------------
__global__ __launch_bounds__(384, 1) void k_gru(
    const float* __restrict__ S_g, const float* __restrict__ dw2,
    const float* __restrict__ db2, const float* __restrict__ Tg,
    const float* __restrict__ a1w, const float* __restrict__ a1b,
    const float* __restrict__ a2w, const float* __restrict__ a2b,
    const float* __restrict__ wih, const float* __restrict__ whh,
    const float* __restrict__ bih, const float* __restrict__ bhh,
    const float* __restrict__ fcw, const float* __restrict__ fcb,
    const float* __restrict__ lvw, const float* __restrict__ lvb,
    const float* __restrict__ init_token, float* __restrict__ out)
{
    const int b   = blockIdx.x;
    const int tid = threadIdx.x;

    __shared__ __align__(16) float Ssh[4][64];
    __shared__ __align__(16) float msh[4][128];
    __shared__ __align__(16) float evs[4][128];
    __shared__ __align__(16) float hl[128];
    __shared__ float ghl[384];
    __shared__ float scoreL[4];
    __shared__ float unc_part[2][4];
    __shared__ float wgt[4];
    __shared__ float redL[2][2];
    __shared__ float tokL;

    if (tid < 256) {
        int s = tid >> 6, cc = tid & 63;
        Ssh[s][cc] = S_g[(s*256 + b)*64 + cc];
    }
    const float T = Tg[0];
    __syncthreads();

    // recon: out_j = (W2^T S)_j + T*b2_j ; j<128 -> means, j>=128 -> exp(.)
    for (int e = tid; e < 1024; e += 384) {
        int s = e >> 8, j = e & 255;
        float acc = T * db2[s*256 + j];
        const float4* s4 = (const float4*)Ssh[s];
#pragma unroll
        for (int k4 = 0; k4 < 16; ++k4) {
            float4 sv = s4[k4];
            acc += sv.x * dw2[(s*64 + 4*k4 + 0)*256 + j]
                 + sv.y * dw2[(s*64 + 4*k4 + 1)*256 + j]
                 + sv.z * dw2[(s*64 + 4*k4 + 2)*256 + j]
                 + sv.w * dw2[(s*64 + 4*k4 + 3)*256 + j];
        }
        if (j < 128) msh[s][j] = acc;
        else         evs[s][j - 128] = expf(acc);
    }
    __syncthreads();

    // uncertainty = mean(exp(logvar)) per scale
    if (tid < 128) {
        int wv = tid >> 6;
#pragma unroll
        for (int s = 0; s < 4; ++s) {
            float v = evs[s][tid];
#pragma unroll
            for (int off = 32; off > 0; off >>= 1) v += __shfl_xor(v, off);
            if ((tid & 63) == 0) unc_part[wv][s] = v;
        }
    }
    // attention scores: relu(means @ a1w + a1b) @ a2w + a2b
    if (tid < 128) {
        int s = tid >> 5, aq = tid & 31;
        float hd = a1b[aq];
#pragma unroll 4
        for (int i = 0; i < 128; ++i) hd += msh[s][i] * a1w[i*32 + aq];
        hd = fmaxf(hd, 0.f);
        float sc = hd * a2w[aq];
#pragma unroll
        for (int off = 16; off > 0; off >>= 1) sc += __shfl_xor(sc, off);
        if (aq == 0) scoreL[s] = sc + a2b[0];
    }
    __syncthreads();
    if (tid == 0) {
        float sv[4], mx = -1e30f;
#pragma unroll
        for (int s = 0; s < 4; ++s) {
            float u = (unc_part[0][s] + unc_part[1][s]) / 128.f;
            sv[s] = scoreL[s] / (u + 1e-6f);
            mx = fmaxf(mx, sv[s]);
        }
        float se = 0.f, ev[4];
#pragma unroll
        for (int s = 0; s < 4; ++s) { ev[s] = expf(sv[s] - mx); se += ev[s]; }
#pragma unroll
        for (int s = 0; s < 4; ++s) wgt[s] = ev[s] / se;
        tokL = init_token[0];
    }
    __syncthreads();
    if (tid < 128) {
        float f = 0.f;
#pragma unroll
        for (int s = 0; s < 4; ++s) f += wgt[s] * msh[s][tid];
        hl[tid] = f;
    }

    // register-resident GRU weights
    float4 whh4[32];
    const float4* wr = (const float4*)(whh + tid*128);
#pragma unroll
    for (int k = 0; k < 32; ++k) whh4[k] = wr[k];
    float bhhj = bhh[tid];
    float wih_r = 0.f, wih_z = 0.f, wih_n = 0.f;
    float bih_r = 0.f, bih_z = 0.f, bih_n = 0.f;
    float fcwi = 0.f, lvwi = 0.f;
    if (tid < 128) {
        wih_r = wih[tid]; wih_z = wih[128+tid]; wih_n = wih[256+tid];
        bih_r = bih[tid]; bih_z = bih[128+tid]; bih_n = bih[256+tid];
        fcwi  = fcw[tid]; lvwi  = lvw[tid];
    }
    const float fcbv = fcb[0], lvbv = lvb[0];
    __syncthreads();

    for (int t = 0; t < NFH; ++t) {
        float g0 = 0.f, g1 = 0.f, g2 = 0.f, g3 = 0.f;
        const float4* h4 = (const float4*)hl;
#pragma unroll
        for (int k = 0; k < 32; ++k) {
            float4 hv = h4[k];
            float4 wvv = whh4[k];
            g0 += hv.x * wvv.x; g1 += hv.y * wvv.y;
            g2 += hv.z * wvv.z; g3 += hv.w * wvv.w;
        }
        ghl[tid] = ((g0 + g1) + (g2 + g3)) + bhhj;
        __syncthreads();

        if (tid < 128) {
            float tok = tokL;
            float r  = 1.f / (1.f + expf(-(tok*wih_r + bih_r + ghl[tid])));
            float zz = 1.f / (1.f + expf(-(tok*wih_z + bih_z + ghl[128+tid])));
            float n  = tanhf(tok*wih_n + bih_n + r * ghl[256+tid]);
            float hn = (1.f - zz) * n + zz * hl[tid];
            hl[tid] = hn;
            float pp = hn * fcwi, pl = hn * lvwi;
#pragma unroll
            for (int off = 32; off > 0; off >>= 1) {
                pp += __shfl_xor(pp, off);
                pl += __shfl_xor(pl, off);
            }
            int wvx = tid >> 6;
            if ((tid & 63) == 0) { redL[wvx][0] = pp; redL[wvx][1] = pl; }
        }
        __syncthreads();
        if (tid == 0) {
            float pr = redL[0][0] + redL[1][0] + fcbv;
            float pv = redL[0][1] + redL[1][1] + lvbv;
            out[b*NFH + t] = pr;
            out[NB*NFH + b*NFH + t] = pv;
            tokL = pr;
        }
        __syncthreads();
    }
}

// ---------------------------------------------------------------------------
extern "C" void kernel_launch(void* const* d_in, const int* in_sizes, int n_in,
                              void* d_out, int out_size, void* d_ws, size_t ws_size,
                              hipStream_t stream)
{
    const float* x      = (const float*)d_in[0];
    const float* tspan  = (const float*)d_in[1];
    const float* c1w    = (const float*)d_in[2];
    const float* c1b    = (const float*)d_in[3];
    const float* bn1g   = (const float*)d_in[4];
    const float* bn1b   = (const float*)d_in[5];
    const float* c2w    = (const float*)d_in[6];
    const float* c2b    = (const float*)d_in[7];
    const float* bn2g   = (const float*)d_in[8];
    const float* bn2b   = (const float*)d_in[9];
    const float* dw1    = (const float*)d_in[10];
    const float* db1    = (const float*)d_in[11];
    const float* dw2    = (const float*)d_in[12];
    const float* db2    = (const float*)d_in[13];
    const float* a1w    = (const float*)d_in[14];
    const float* a1b    = (const float*)d_in[15];
    const float* a2w    = (const float*)d_in[16];
    const float* a2b    = (const float*)d_in[17];
    const float* wih    = (const float*)d_in[18];
    const float* whh    = (const float*)d_in[19];
    const float* bih    = (const float*)d_in[20];
    const float* bhh    = (const float*)d_in[21];
    const float* fcw    = (const float*)d_in[22];
    const float* fcb    = (const float*)d_in[23];
    const float* lvw    = (const float*)d_in[24];
    const float* lvb    = (const float*)d_in[25];
    const float* itok   = (const float*)d_in[26];

    float* ws    = (float*)d_ws;
    float*  cv2  = ws;                        // 262144  (conv2 raw output)
    float*  tmpA = ws + 262144;               // 262144  (conv1 raw output)
    float*  S_g  = ws + 524288;               // 65536
    float*  Mt   = ws + 589824;               // 16384
    float*  bMg  = ws + 606208;               // 256
    float*  Tg   = ws + 606464;               // 1
    int*    imid = (int*)(ws + 606720);       // 255
    double* pp1  = (double*)(ws + 606976);    // 128 doubles
    double* pp2  = (double*)(ws + 607232);    // 128 doubles
    float*  st1  = ws + 607488;               // 8
    float*  st2  = ws + 607496;               // 8

    k_d1<<<64, 256, 0, stream>>>(x, c1w, c1b, tmpA, pp1);
    k_d2<<<1, 256, 0, stream>>>(tspan, pp1, st1, imid, Tg);
    k_d3<<<64, 256, 0, stream>>>(tmpA, st1, bn1g, bn1b, c2w, c2b, cv2, pp2);
    k_d4<<<1, 64, 0, stream>>>(pp2, st2);
    k_mat<<<256, 64, 0, stream>>>(dw1, dw2, db2, Mt, bMg);
    k_ode<<<1024, 64, 0, stream>>>(cv2, st2, bn2g, bn2b, tspan, imid,
                                   Mt, bMg, dw1, db1, S_g);
    k_gru<<<256, 384, 0, stream>>>(S_g, dw2, db2, Tg, a1w, a1b, a2w, a2b,
                                   wih, whh, bih, bhh, fcw, fcb, lvw, lvb,
                                   itok, (float*)d_out);
}